// Round 1
// baseline (640.884 us; speedup 1.0000x reference)
//
#include <hip/hip_runtime.h>
#include <math.h>

#define N_    8
#define CH    256
#define CL    512
#define NECK  64
#define H_    128
#define W_    128
#define HW    16384
#define HWS   1024
#define EPSB  1e-5f
#define SC31  (31.0f/127.0f)

__device__ __forceinline__ float sigmoidf_(float x){ return 1.0f/(1.0f + __expf(-x)); }

// bilinear upsample (align_corners=True) from a 32x32 plane to 128x128 coords
__device__ __forceinline__ float bilin32(const float* __restrict__ src, int h, int w){
    float y = h * SC31, x = w * SC31;
    int y0 = (int)y, x0 = (int)x;
    int y1 = min(y0+1, 31), x1 = min(x0+1, 31);
    float fy = y - (float)y0, fx = x - (float)x0;
    float a = src[y0*32+x0], b = src[y0*32+x1];
    float c = src[y1*32+x0], d = src[y1*32+x1];
    float r0 = a + (b-a)*fx;
    float r1 = c + (d-c)*fx;
    return r0 + (r1-r0)*fy;
}

// ---------------- K1: big conv: x[8,256,16384] -> value/query/query2 [8,64,16384]
__global__ __launch_bounds__(256) void k_conv_big(
    const float* __restrict__ x,
    const float* __restrict__ wv1, const float* __restrict__ wq1, const float* __restrict__ wq2,
    const float* __restrict__ s1, const float* __restrict__ b1,
    const float* __restrict__ s2, const float* __restrict__ b2,
    float* __restrict__ value, float* __restrict__ query, float* __restrict__ query2)
{
    __shared__ float xt[32][64];     // 8KB
    __shared__ float wt[32][196];    // 25KB  (192 outputs + pad)
    int T = blockIdx.x;
    int n = T >> 8;                  // 256 pixel-tiles per image
    int pix0 = (T & 255) * 64;
    int t = threadIdx.x;
    int to = t >> 4;                 // 0..15 -> o = to*12
    int tp = t & 15;                 // 0..15 -> p = tp*4
    float acc[12][4];
    #pragma unroll
    for (int i=0;i<12;i++){ acc[i][0]=0.f;acc[i][1]=0.f;acc[i][2]=0.f;acc[i][3]=0.f; }

    const float* xb = x + (size_t)n*CH*HW + pix0;
    for (int cc=0; cc<8; ++cc){
        #pragma unroll
        for (int i=0;i<8;i++){       // 32*64 = 2048 elems
            int e = i*256 + t;
            int c = e >> 6, p = e & 63;
            xt[c][p] = xb[(size_t)(cc*32 + c)*HW + p];
        }
        #pragma unroll
        for (int i=0;i<24;i++){      // 192*32 = 6144 elems
            int e = i*256 + t;
            int o = e >> 5, c = e & 31;
            const float* wsrc = (o < 64) ? (wv1 + (size_t)o*CH)
                              : (o < 128) ? (wq1 + (size_t)(o-64)*CH)
                                          : (wq2 + (size_t)(o-128)*CH);
            wt[c][o] = wsrc[cc*32 + c];
        }
        __syncthreads();
        #pragma unroll 4
        for (int c=0;c<32;c++){
            float4 xv = *(const float4*)&xt[c][tp*4];
            const float4* wr = (const float4*)&wt[c][to*12];
            float4 wa = wr[0], wb = wr[1], wc4 = wr[2];
            float wv[12] = {wa.x,wa.y,wa.z,wa.w, wb.x,wb.y,wb.z,wb.w, wc4.x,wc4.y,wc4.z,wc4.w};
            #pragma unroll
            for (int i=0;i<12;i++){
                acc[i][0] = fmaf(wv[i], xv.x, acc[i][0]);
                acc[i][1] = fmaf(wv[i], xv.y, acc[i][1]);
                acc[i][2] = fmaf(wv[i], xv.z, acc[i][2]);
                acc[i][3] = fmaf(wv[i], xv.w, acc[i][3]);
            }
        }
        __syncthreads();
    }
    float inv = rsqrtf(1.0f + EPSB);
    #pragma unroll
    for (int i=0;i<12;i++){
        int o = to*12 + i;
        int g = o >> 6, oc = o & 63;
        float4 r = make_float4(acc[i][0],acc[i][1],acc[i][2],acc[i][3]);
        float* dst;
        if (g == 0){
            dst = value;
        } else {
            float sc, bb;
            if (g == 1){ sc = s1[oc]*inv; bb = b1[oc]; dst = query; }
            else       { sc = s2[oc]*inv; bb = b2[oc]; dst = query2; }
            r.x = fmaxf(fmaf(r.x,sc,bb), 0.f);
            r.y = fmaxf(fmaf(r.y,sc,bb), 0.f);
            r.z = fmaxf(fmaf(r.z,sc,bb), 0.f);
            r.w = fmaxf(fmaf(r.w,sc,bb), 0.f);
        }
        *(float4*)&dst[(size_t)(n*NECK + oc)*HW + pix0 + tp*4] = r;
    }
}

// ---------------- K2: small conv: other[8,512,1024] -> k1small/k2small [8,64,1024] (bn_relu applied)
__global__ __launch_bounds__(256) void k_conv_small(
    const float* __restrict__ x,
    const float* __restrict__ wk1, const float* __restrict__ wk2,
    const float* __restrict__ sk1, const float* __restrict__ bk1,
    const float* __restrict__ sk2, const float* __restrict__ bk2,
    float* __restrict__ k1small, float* __restrict__ k2small)
{
    __shared__ float xt[64][64];     // 16KB
    __shared__ float wt[64][132];    // 33.8KB
    int T = blockIdx.x;
    int n = T >> 4;                  // 16 pixel-tiles per image
    int pix0 = (T & 15) * 64;
    int t = threadIdx.x;
    int to = t >> 4;                 // o = to*8
    int tp = t & 15;                 // p = tp*4
    float acc[8][4];
    #pragma unroll
    for (int i=0;i<8;i++){ acc[i][0]=0.f;acc[i][1]=0.f;acc[i][2]=0.f;acc[i][3]=0.f; }

    const float* xb = x + (size_t)n*CL*HWS + pix0;
    for (int cc=0; cc<8; ++cc){
        #pragma unroll
        for (int i=0;i<16;i++){      // 64*64
            int e = i*256 + t;
            int c = e >> 6, p = e & 63;
            xt[c][p] = xb[(size_t)(cc*64 + c)*HWS + p];
        }
        #pragma unroll
        for (int i=0;i<32;i++){      // 128*64
            int e = i*256 + t;
            int o = e >> 6, c = e & 63;
            const float* wsrc = (o < 64) ? (wk1 + (size_t)o*CL) : (wk2 + (size_t)(o-64)*CL);
            wt[c][o] = wsrc[cc*64 + c];
        }
        __syncthreads();
        #pragma unroll 4
        for (int c=0;c<64;c++){
            float4 xv = *(const float4*)&xt[c][tp*4];
            const float4* wr = (const float4*)&wt[c][to*8];
            float4 wa = wr[0], wb = wr[1];
            float wv[8] = {wa.x,wa.y,wa.z,wa.w, wb.x,wb.y,wb.z,wb.w};
            #pragma unroll
            for (int i=0;i<8;i++){
                acc[i][0] = fmaf(wv[i], xv.x, acc[i][0]);
                acc[i][1] = fmaf(wv[i], xv.y, acc[i][1]);
                acc[i][2] = fmaf(wv[i], xv.z, acc[i][2]);
                acc[i][3] = fmaf(wv[i], xv.w, acc[i][3]);
            }
        }
        __syncthreads();
    }
    float inv = rsqrtf(1.0f + EPSB);
    #pragma unroll
    for (int i=0;i<8;i++){
        int o = to*8 + i;
        int g = o >> 6, oc = o & 63;
        float sc = (g ? sk2[oc] : sk1[oc]) * inv;
        float bb =  g ? bk2[oc] : bk1[oc];
        float4 r;
        r.x = fmaxf(fmaf(acc[i][0],sc,bb), 0.f);
        r.y = fmaxf(fmaf(acc[i][1],sc,bb), 0.f);
        r.z = fmaxf(fmaf(acc[i][2],sc,bb), 0.f);
        r.w = fmaxf(fmaf(acc[i][3],sc,bb), 0.f);
        float* dst = g ? k2small : k1small;
        *(float4*)&dst[(size_t)(n*NECK + oc)*HWS + pix0 + tp*4] = r;
    }
}

// ---------------- K3a: scale-1 gates (P=16 patches of 32x32), channels 0..31
__global__ __launch_bounds__(256) void k_gate1(
    const float* __restrict__ query, const float* __restrict__ k1small,
    float* __restrict__ gate1)
{
    __shared__ float ksm[1024];
    __shared__ float qt[16][260];
    __shared__ float kt[16][260];
    __shared__ float simM[16][17];
    int b = blockIdx.x;
    int n = b >> 5, c = b & 31;
    int t = threadIdx.x;
    const float* ks = k1small + (size_t)(n*NECK + c)*HWS;
    #pragma unroll
    for (int i=0;i<4;i++) ksm[i*256+t] = ks[i*256+t];
    const float* qb = query + (size_t)(n*NECK + c)*HW;
    int p_ = t >> 4, q_ = t & 15;
    float sim = 0.f;
    for (int lc=0; lc<4; ++lc){
        __syncthreads();
        #pragma unroll
        for (int i=0;i<16;i++){      // 16 patches x 256 pix-per-chunk
            int p = i, s = t;
            int l = lc*256 + s;
            int ly = l >> 5, lx = l & 31;
            int h = (p>>2)*32 + ly, w = (p&3)*32 + lx;
            qt[p][s] = qb[h*W_ + w];
            kt[p][s] = bilin32(ksm, h, w);
        }
        __syncthreads();
        const float4* q4 = (const float4*)qt[p_];
        const float4* k4 = (const float4*)kt[q_];
        #pragma unroll 8
        for (int s4=0; s4<64; ++s4){
            float4 a = q4[s4], bb = k4[s4];
            sim += a.x*bb.x + a.y*bb.y + a.z*bb.z + a.w*bb.w;
        }
    }
    simM[p_][q_] = sigmoidf_(sim);
    __syncthreads();
    if (t < 16){
        float rs=0.f, cs=0.f;
        #pragma unroll
        for (int q=0;q<16;q++) rs += simM[t][q];
        #pragma unroll
        for (int p=0;p<16;p++) cs += simM[p][t];
        gate1[(size_t)(n*32 + c)*16 + t] = (rs + cs) * (1.0f/16.0f);
    }
}

// ---------------- K3b: scale-2 gates (P=64 patches of 16x16), channels 32..63
__global__ __launch_bounds__(256) void k_gate2(
    const float* __restrict__ query, const float* __restrict__ k1small,
    float* __restrict__ gate2)
{
    __shared__ float ksm[1024];
    __shared__ float qt[64][68];
    __shared__ float kt[64][68];
    __shared__ float simM[64][65];
    int b = blockIdx.x;
    int n = b >> 5, cl = b & 31, c = 32 + cl;
    int t = threadIdx.x;
    const float* ks = k1small + (size_t)(n*NECK + c)*HWS;
    #pragma unroll
    for (int i=0;i<4;i++) ksm[i*256+t] = ks[i*256+t];
    const float* qb = query + (size_t)(n*NECK + c)*HW;
    int p_ = t >> 2, qb_ = t & 3;
    float acc[16];
    #pragma unroll
    for (int j=0;j<16;j++) acc[j]=0.f;
    for (int lc=0; lc<4; ++lc){
        __syncthreads();
        #pragma unroll
        for (int i=0;i<16;i++){      // 64 patches x 64 pix-per-chunk
            int e = i*256 + t;
            int p = e >> 6, s = e & 63;
            int l = lc*64 + s;
            int h = (p>>3)*16 + (l>>4), w = (p&7)*16 + (l&15);
            qt[p][s] = qb[h*W_ + w];
            kt[p][s] = bilin32(ksm, h, w);
        }
        __syncthreads();
        const float4* q4 = (const float4*)qt[p_];
        #pragma unroll 4
        for (int s4=0; s4<16; ++s4){
            float4 a = q4[s4];
            #pragma unroll
            for (int j=0;j<16;j++){
                float4 bb = ((const float4*)kt[qb_ + 4*j])[s4];
                acc[j] += a.x*bb.x + a.y*bb.y + a.z*bb.z + a.w*bb.w;
            }
        }
    }
    #pragma unroll
    for (int j=0;j<16;j++) simM[p_][qb_ + 4*j] = sigmoidf_(acc[j]);
    __syncthreads();
    if (t < 64){
        float rs=0.f, cs=0.f;
        for (int q=0;q<64;q++) rs += simM[t][q];
        for (int p=0;p<64;p++) cs += simM[p][t];
        gate2[(size_t)(n*32 + cl)*64 + t] = (rs + cs) * (1.0f/64.0f);
    }
}

// ---------------- K4: build context (gates + dense sigmoid branch) and final conv wz[256,128]
__global__ __launch_bounds__(256) void k_final(
    const float* __restrict__ value, const float* __restrict__ query2,
    const float* __restrict__ k2small,
    const float* __restrict__ gate1, const float* __restrict__ gate2,
    const float* __restrict__ wz,
    const float* __restrict__ alpha_p, const float* __restrict__ gamma_p,
    float* __restrict__ out)
{
    __shared__ float ctx[128][64];   // 32KB
    __shared__ float wzt[128][64];   // 32KB
    int T = blockIdx.x;
    int n = T >> 8;
    int pix0 = (T & 255) * 64;
    int h = pix0 >> 7;               // whole tile shares one h row (64 | 128)
    int w0 = pix0 & 127;
    int t = threadIdx.x;
    float alpha = alpha_p[0], gamma = gamma_p[0];

    // phase 1: context [128][64]
    int p = t & 63;
    int w = w0 + p;
    int pix = pix0 + p;
    int patch1 = (h>>5)*4 + (w>>5);
    int patch2 = (h>>4)*8 + (w>>4);
    #pragma unroll
    for (int i=0;i<32;i++){
        int j = i*4 + (t>>6);
        float v;
        if (j < 64){
            float g = (j < 32) ? gate1[(size_t)(n*32 + j)*16 + patch1]
                               : gate2[(size_t)(n*32 + (j-32))*64 + patch2];
            v = alpha * g * value[(size_t)(n*NECK + j)*HW + pix];
        } else {
            int c = j - 64;
            float q2 = query2[(size_t)(n*NECK + c)*HW + pix];
            float kv = bilin32(k2small + (size_t)(n*NECK + c)*HWS, h, w);
            v = gamma * value[(size_t)(n*NECK + c)*HW + pix] * sigmoidf_(q2*kv);
        }
        ctx[j][p] = v;
    }

    // phase 2: out[o,pix] = sum_j wz[o][j] * ctx[j][pix], o chunked by 64
    int to = t >> 4, tp = t & 15;    // o = oc*64 + to*4 + i ; p = tp*4 + q
    for (int oc=0; oc<4; ++oc){
        __syncthreads();             // protects ctx (first iter) and wzt reuse
        #pragma unroll
        for (int i=0;i<32;i++){      // 64 o x 128 j
            int e = i*256 + t;
            int ol = e >> 7, j = e & 127;
            wzt[j][ol] = wz[(size_t)(oc*64 + ol)*128 + j];
        }
        __syncthreads();
        float acc[4][4];
        #pragma unroll
        for (int i=0;i<4;i++){ acc[i][0]=0.f;acc[i][1]=0.f;acc[i][2]=0.f;acc[i][3]=0.f; }
        #pragma unroll 4
        for (int j=0;j<128;j++){
            float4 wv = *(const float4*)&wzt[j][to*4];
            float4 cv = *(const float4*)&ctx[j][tp*4];
            float wv4[4] = {wv.x,wv.y,wv.z,wv.w};
            #pragma unroll
            for (int i=0;i<4;i++){
                acc[i][0] = fmaf(wv4[i], cv.x, acc[i][0]);
                acc[i][1] = fmaf(wv4[i], cv.y, acc[i][1]);
                acc[i][2] = fmaf(wv4[i], cv.z, acc[i][2]);
                acc[i][3] = fmaf(wv4[i], cv.w, acc[i][3]);
            }
        }
        #pragma unroll
        for (int i=0;i<4;i++){
            int o = oc*64 + to*4 + i;
            *(float4*)&out[((size_t)n*CH + o)*HW + pix0 + tp*4] =
                make_float4(acc[i][0],acc[i][1],acc[i][2],acc[i][3]);
        }
    }
}

extern "C" void kernel_launch(void* const* d_in, const int* in_sizes, int n_in,
                              void* d_out, int out_size, void* d_ws, size_t ws_size,
                              hipStream_t stream) {
    const float* x0  = (const float*)d_in[0];
    const float* xo  = (const float*)d_in[1];
    const float* wq1 = (const float*)d_in[2];
    const float* s1  = (const float*)d_in[3];
    const float* b1  = (const float*)d_in[4];
    const float* wk1 = (const float*)d_in[5];
    const float* sk1 = (const float*)d_in[6];
    const float* bk1 = (const float*)d_in[7];
    const float* wv1 = (const float*)d_in[8];
    const float* wq2 = (const float*)d_in[9];
    const float* s2  = (const float*)d_in[10];
    const float* b2  = (const float*)d_in[11];
    const float* wk2 = (const float*)d_in[12];
    const float* sk2 = (const float*)d_in[13];
    const float* bk2 = (const float*)d_in[14];
    const float* wz  = (const float*)d_in[15];
    const float* alp = (const float*)d_in[16];
    const float* gam = (const float*)d_in[17];

    float* ws = (float*)d_ws;
    float* value  = ws;                    // 8*64*16384 = 8388608
    float* query  = ws + 8388608;
    float* query2 = ws + 16777216;
    float* k1s    = ws + 25165824;         // 8*64*1024 = 524288
    float* k2s    = ws + 25690112;
    float* g1     = ws + 26214400;         // 8*32*16
    float* g2     = ws + 26218496;         // 8*32*64

    k_conv_big  <<<dim3(2048), dim3(256), 0, stream>>>(x0, wv1, wq1, wq2, s1, b1, s2, b2,
                                                       value, query, query2);
    k_conv_small<<<dim3(128),  dim3(256), 0, stream>>>(xo, wk1, wk2, sk1, bk1, sk2, bk2,
                                                       k1s, k2s);
    k_gate1     <<<dim3(256),  dim3(256), 0, stream>>>(query, k1s, g1);
    k_gate2     <<<dim3(256),  dim3(256), 0, stream>>>(query, k1s, g2);
    k_final     <<<dim3(2048), dim3(256), 0, stream>>>(value, query2, k2s, g1, g2, wz,
                                                       alp, gam, (float*)d_out);
}

// Round 2
// 415.309 us; speedup vs baseline: 1.5432x; 1.5432x over previous
//
#include <hip/hip_runtime.h>
#include <math.h>
#include <stdint.h>

#define N_    8
#define CH    256
#define CL    512
#define NECK  64
#define H_    128
#define W_    128
#define HW    16384
#define HWS   1024
#define EPSB  1e-5f
#define SC31  (31.0f/127.0f)

typedef unsigned short ushort_t;
typedef __attribute__((ext_vector_type(8))) short bf16x8;
typedef __attribute__((ext_vector_type(4))) float f32x4;

__device__ __forceinline__ float sigmoidf_(float x){ return 1.0f/(1.0f + __expf(-x)); }

__device__ __forceinline__ ushort_t f2bf(float x){
    union { float f; uint32_t u; } v; v.f = x;
    uint32_t r = (v.u + 0x7FFFu + ((v.u >> 16) & 1u)) >> 16;
    return (ushort_t)r;
}
__device__ __forceinline__ float bf2f(ushort_t b){
    union { uint32_t u; float f; } v; v.u = ((uint32_t)b) << 16;
    return v.f;
}

__device__ __forceinline__ void gload16(const void* g, void* l){
    __builtin_amdgcn_global_load_lds((const __attribute__((address_space(1))) void*)g,
                                     (__attribute__((address_space(3))) void*)l, 16, 0, 0);
}

// bilinear upsample (align_corners=True) from a 32x32 plane to 128x128 coords
__device__ __forceinline__ float bilin32(const float* __restrict__ src, int h, int w){
    float y = h * SC31, x = w * SC31;
    int y0 = (int)y, x0 = (int)x;
    int y1 = min(y0+1, 31), x1 = min(x0+1, 31);
    float fy = y - (float)y0, fx = x - (float)x0;
    float a = src[y0*32+x0], b = src[y0*32+x1];
    float c = src[y1*32+x0], d = src[y1*32+x1];
    float r0 = a + (b-a)*fx;
    float r1 = c + (d-c)*fx;
    return r0 + (r1-r0)*fy;
}

// ---------------- prep: pack big-conv weights [192][256] bf16 (rows: wv1, wq1, wq2)
__global__ __launch_bounds__(256) void k_wprep(
    const float* __restrict__ wv1, const float* __restrict__ wq1, const float* __restrict__ wq2,
    ushort_t* __restrict__ Wbig)
{
    int t = blockIdx.x*256 + threadIdx.x;          // 0..49151
    int o = t >> 8, c = t & 255;
    const float* w = (o < 64) ? (wv1 + (size_t)o*CH)
                   : (o < 128) ? (wq1 + (size_t)(o-64)*CH)
                               : (wq2 + (size_t)(o-128)*CH);
    Wbig[t] = f2bf(w[c]);
}

// ---------------- prep: transpose+convert x[2img][256][16384] f32 -> XT[2img][16384][256] bf16
__global__ __launch_bounds__(256) void k_transpose(
    const float* __restrict__ src, ushort_t* __restrict__ dst)
{
    __shared__ ushort_t tile[64][66];
    int b = blockIdx.x;                 // 2 * 4 * 256 tiles
    int n = b >> 10;                    // 1024 tiles per image
    int r = b & 1023;
    int cb = (r >> 8) << 6;             // 4 c-tiles
    int pb = (r & 255) << 6;            // 256 p-tiles
    int t = threadIdx.x;
    const float* s = src + ((size_t)n*CH + cb)*HW + pb;
    int pl = t & 63, cl = t >> 6;       // cl 0..3
    #pragma unroll
    for (int i=0;i<16;i++){
        int c = cl*16 + i;
        tile[c][pl] = f2bf(s[(size_t)c*HW + pl]);
    }
    __syncthreads();
    ushort_t* d = dst + ((size_t)n*HW + pb)*CH + cb;
    int c2 = (t & 31)*2, pl2 = t >> 5;  // pl2 0..7
    #pragma unroll
    for (int i=0;i<8;i++){
        int p = pl2*8 + i;
        uint32_t v = (uint32_t)tile[c2][p] | ((uint32_t)tile[c2+1][p] << 16);
        *(uint32_t*)&d[(size_t)p*CH + c2] = v;
    }
}

// ---------------- K1: bf16 MFMA GEMM: C[192][pix] = Wbig[192][256] * XT^T ; BN=128, BK=64
__global__ __launch_bounds__(512) void k_gemm_big(
    const ushort_t* __restrict__ XT,   // [2][16384][256] bf16 chunk
    const ushort_t* __restrict__ Wb,   // [192][256] bf16
    const float* __restrict__ s1, const float* __restrict__ b1,
    const float* __restrict__ s2, const float* __restrict__ b2,
    ushort_t* __restrict__ value, ushort_t* __restrict__ query, ushort_t* __restrict__ query2,
    int nbase)
{
    __shared__ ushort_t At[192*64];    // 24KB (swizzled)
    __shared__ ushort_t Bt[128*64];    // 16KB (swizzled)
    int blk = blockIdx.x;
    int nl = blk >> 7;                 // local image 0..1
    int pix0 = (blk & 127) << 7;       // 128-pixel tile
    int t = threadIdx.x;
    int wid = t >> 6, lane = t & 63;
    int wm = wid >> 1, wn = wid & 1;   // 4(M) x 2(N) waves; wave tile 48 x 64

    f32x4 acc[3][4];
    #pragma unroll
    for (int m=0;m<3;m++)
        #pragma unroll
        for (int nn=0;nn<4;nn++) acc[m][nn] = (f32x4){0.f,0.f,0.f,0.f};

    const ushort_t* Xb = XT + ((size_t)nl*HW + pix0)*CH;
    for (int kt=0; kt<4; ++kt){
        int c0 = kt*64;
        // stage A: 1536 16B-chunks, 3 per thread; pre-swizzled source (rule #21)
        #pragma unroll
        for (int i=0;i<3;i++){
            int g = i*512 + t;
            int s = g ^ ((g>>3)&7);
            gload16(Wb + (size_t)(s>>3)*CH + c0 + (s&7)*8, (char*)At + g*16);
        }
        // stage B: 1024 chunks, 2 per thread
        #pragma unroll
        for (int i=0;i<2;i++){
            int g = i*512 + t;
            int s = g ^ ((g>>3)&7);
            gload16(Xb + (size_t)(s>>3)*CH + c0 + (s&7)*8, (char*)Bt + g*16);
        }
        __syncthreads();
        #pragma unroll
        for (int ks=0; ks<2; ++ks){
            bf16x8 a[3], b[4];
            #pragma unroll
            for (int m=0;m<3;m++){
                int row = wm*48 + m*16 + (lane&15);
                int off = (row*128 + ks*64 + (lane>>4)*16) ^ ((row&7)<<4);
                a[m] = *(const bf16x8*)((const char*)At + off);
            }
            #pragma unroll
            for (int nn=0;nn<4;nn++){
                int row = wn*64 + nn*16 + (lane&15);
                int off = (row*128 + ks*64 + (lane>>4)*16) ^ ((row&7)<<4);
                b[nn] = *(const bf16x8*)((const char*)Bt + off);
            }
            #pragma unroll
            for (int m=0;m<3;m++)
                #pragma unroll
                for (int nn=0;nn<4;nn++)
                    acc[m][nn] = __builtin_amdgcn_mfma_f32_16x16x32_bf16(a[m], b[nn], acc[m][nn], 0, 0, 0);
        }
        __syncthreads();
    }
    // epilogue: C/D layout col=lane&15 (pix), row=(lane>>4)*4+reg (o)
    int n = nbase + nl;
    float inv = rsqrtf(1.0f + EPSB);
    #pragma unroll
    for (int m=0;m<3;m++){
        int obase = wm*48 + m*16 + ((lane>>4)<<2);
        #pragma unroll
        for (int r=0;r<4;r++){
            int o = obase + r;
            int grp = o >> 6, oc = o & 63;
            float sc = 1.f, bb = 0.f;
            ushort_t* dst;
            if (grp == 0) dst = value;
            else if (grp == 1){ sc = s1[oc]*inv; bb = b1[oc]; dst = query; }
            else              { sc = s2[oc]*inv; bb = b2[oc]; dst = query2; }
            #pragma unroll
            for (int nn=0;nn<4;nn++){
                int pix = pix0 + wn*64 + nn*16 + (lane&15);
                float v = acc[m][nn][r];
                if (grp) v = fmaxf(fmaf(v, sc, bb), 0.f);
                dst[((size_t)(n*NECK + oc))*HW + pix] = f2bf(v);
            }
        }
    }
}

// ---------------- K2: small conv (fp32, unchanged): other[8,512,1024] -> k1s/k2s fp32
__global__ __launch_bounds__(256) void k_conv_small(
    const float* __restrict__ x,
    const float* __restrict__ wk1, const float* __restrict__ wk2,
    const float* __restrict__ sk1, const float* __restrict__ bk1,
    const float* __restrict__ sk2, const float* __restrict__ bk2,
    float* __restrict__ k1small, float* __restrict__ k2small)
{
    __shared__ float xt[64][64];
    __shared__ float wt[64][132];
    int T = blockIdx.x;
    int n = T >> 4;
    int pix0 = (T & 15) * 64;
    int t = threadIdx.x;
    int to = t >> 4;
    int tp = t & 15;
    float acc[8][4];
    #pragma unroll
    for (int i=0;i<8;i++){ acc[i][0]=0.f;acc[i][1]=0.f;acc[i][2]=0.f;acc[i][3]=0.f; }

    const float* xb = x + (size_t)n*CL*HWS + pix0;
    for (int cc=0; cc<8; ++cc){
        #pragma unroll
        for (int i=0;i<16;i++){
            int e = i*256 + t;
            int c = e >> 6, p = e & 63;
            xt[c][p] = xb[(size_t)(cc*64 + c)*HWS + p];
        }
        #pragma unroll
        for (int i=0;i<32;i++){
            int e = i*256 + t;
            int o = e >> 6, c = e & 63;
            const float* wsrc = (o < 64) ? (wk1 + (size_t)o*CL) : (wk2 + (size_t)(o-64)*CL);
            wt[c][o] = wsrc[cc*64 + c];
        }
        __syncthreads();
        #pragma unroll 4
        for (int c=0;c<64;c++){
            float4 xv = *(const float4*)&xt[c][tp*4];
            const float4* wr = (const float4*)&wt[c][to*8];
            float4 wa = wr[0], wb = wr[1];
            float wv[8] = {wa.x,wa.y,wa.z,wa.w, wb.x,wb.y,wb.z,wb.w};
            #pragma unroll
            for (int i=0;i<8;i++){
                acc[i][0] = fmaf(wv[i], xv.x, acc[i][0]);
                acc[i][1] = fmaf(wv[i], xv.y, acc[i][1]);
                acc[i][2] = fmaf(wv[i], xv.z, acc[i][2]);
                acc[i][3] = fmaf(wv[i], xv.w, acc[i][3]);
            }
        }
        __syncthreads();
    }
    float inv = rsqrtf(1.0f + EPSB);
    #pragma unroll
    for (int i=0;i<8;i++){
        int o = to*8 + i;
        int g = o >> 6, oc = o & 63;
        float sc = (g ? sk2[oc] : sk1[oc]) * inv;
        float bb =  g ? bk2[oc] : bk1[oc];
        float4 r;
        r.x = fmaxf(fmaf(acc[i][0],sc,bb), 0.f);
        r.y = fmaxf(fmaf(acc[i][1],sc,bb), 0.f);
        r.z = fmaxf(fmaf(acc[i][2],sc,bb), 0.f);
        r.w = fmaxf(fmaf(acc[i][3],sc,bb), 0.f);
        float* dst = g ? k2small : k1small;
        *(float4*)&dst[(size_t)(n*NECK + oc)*HWS + pix0 + tp*4] = r;
    }
}

// ---------------- K3a: scale-1 gates (P=16 patches of 32x32), channels 0..31
__global__ __launch_bounds__(256) void k_gate1(
    const ushort_t* __restrict__ query, const float* __restrict__ k1small,
    float* __restrict__ gate1)
{
    __shared__ float ksm[1024];
    __shared__ float qt[16][260];
    __shared__ float kt[16][260];
    __shared__ float simM[16][17];
    int b = blockIdx.x;
    int n = b >> 5, c = b & 31;
    int t = threadIdx.x;
    const float* ks = k1small + (size_t)(n*NECK + c)*HWS;
    #pragma unroll
    for (int i=0;i<4;i++) ksm[i*256+t] = ks[i*256+t];
    const ushort_t* qb = query + (size_t)(n*NECK + c)*HW;
    int p_ = t >> 4, q_ = t & 15;
    float sim = 0.f;
    for (int lc=0; lc<4; ++lc){
        __syncthreads();
        #pragma unroll
        for (int i=0;i<16;i++){
            int p = i, s = t;
            int l = lc*256 + s;
            int ly = l >> 5, lx = l & 31;
            int h = (p>>2)*32 + ly, w = (p&3)*32 + lx;
            qt[p][s] = bf2f(qb[h*W_ + w]);
            kt[p][s] = bilin32(ksm, h, w);
        }
        __syncthreads();
        const float4* q4 = (const float4*)qt[p_];
        const float4* k4 = (const float4*)kt[q_];
        #pragma unroll 8
        for (int s4=0; s4<64; ++s4){
            float4 a = q4[s4], bb = k4[s4];
            sim += a.x*bb.x + a.y*bb.y + a.z*bb.z + a.w*bb.w;
        }
    }
    simM[p_][q_] = sigmoidf_(sim);
    __syncthreads();
    if (t < 16){
        float rs=0.f, cs=0.f;
        #pragma unroll
        for (int q=0;q<16;q++) rs += simM[t][q];
        #pragma unroll
        for (int p=0;p<16;p++) cs += simM[p][t];
        gate1[(size_t)(n*32 + c)*16 + t] = (rs + cs) * (1.0f/16.0f);
    }
}

// ---------------- K3b: scale-2 gates (P=64 patches of 16x16), channels 32..63
__global__ __launch_bounds__(256) void k_gate2(
    const ushort_t* __restrict__ query, const float* __restrict__ k1small,
    float* __restrict__ gate2)
{
    __shared__ float ksm[1024];
    __shared__ float qt[64][68];
    __shared__ float kt[64][68];
    __shared__ float simM[64][65];
    int b = blockIdx.x;
    int n = b >> 5, cl = b & 31, c = 32 + cl;
    int t = threadIdx.x;
    const float* ks = k1small + (size_t)(n*NECK + c)*HWS;
    #pragma unroll
    for (int i=0;i<4;i++) ksm[i*256+t] = ks[i*256+t];
    const ushort_t* qb = query + (size_t)(n*NECK + c)*HW;
    int p_ = t >> 2, qb_ = t & 3;
    float acc[16];
    #pragma unroll
    for (int j=0;j<16;j++) acc[j]=0.f;
    for (int lc=0; lc<4; ++lc){
        __syncthreads();
        #pragma unroll
        for (int i=0;i<16;i++){
            int e = i*256 + t;
            int p = e >> 6, s = e & 63;
            int l = lc*64 + s;
            int h = (p>>3)*16 + (l>>4), w = (p&7)*16 + (l&15);
            qt[p][s] = bf2f(qb[h*W_ + w]);
            kt[p][s] = bilin32(ksm, h, w);
        }
        __syncthreads();
        const float4* q4 = (const float4*)qt[p_];
        #pragma unroll 4
        for (int s4=0; s4<16; ++s4){
            float4 a = q4[s4];
            #pragma unroll
            for (int j=0;j<16;j++){
                float4 bb = ((const float4*)kt[qb_ + 4*j])[s4];
                acc[j] += a.x*bb.x + a.y*bb.y + a.z*bb.z + a.w*bb.w;
            }
        }
    }
    #pragma unroll
    for (int j=0;j<16;j++) simM[p_][qb_ + 4*j] = sigmoidf_(acc[j]);
    __syncthreads();
    if (t < 64){
        float rs=0.f, cs=0.f;
        for (int q=0;q<64;q++) rs += simM[t][q];
        for (int p=0;p<64;p++) cs += simM[p][t];
        gate2[(size_t)(n*32 + cl)*64 + t] = (rs + cs) * (1.0f/64.0f);
    }
}

// ---------------- K4: build context + final conv wz[256,128] (fp32 VALU)
__global__ __launch_bounds__(256) void k_final(
    const ushort_t* __restrict__ value, const ushort_t* __restrict__ query2,
    const float* __restrict__ k2small,
    const float* __restrict__ gate1, const float* __restrict__ gate2,
    const float* __restrict__ wz,
    const float* __restrict__ alpha_p, const float* __restrict__ gamma_p,
    float* __restrict__ out)
{
    __shared__ float ctx[128][64];
    __shared__ float wzt[128][64];
    int T = blockIdx.x;
    int n = T >> 8;
    int pix0 = (T & 255) * 64;
    int h = pix0 >> 7;
    int w0 = pix0 & 127;
    int t = threadIdx.x;
    float alpha = alpha_p[0], gamma = gamma_p[0];

    int p = t & 63;
    int w = w0 + p;
    int pix = pix0 + p;
    int patch1 = (h>>5)*4 + (w>>5);
    int patch2 = (h>>4)*8 + (w>>4);
    #pragma unroll
    for (int i=0;i<32;i++){
        int j = i*4 + (t>>6);
        float v;
        if (j < 64){
            float g = (j < 32) ? gate1[(size_t)(n*32 + j)*16 + patch1]
                               : gate2[(size_t)(n*32 + (j-32))*64 + patch2];
            v = alpha * g * bf2f(value[(size_t)(n*NECK + j)*HW + pix]);
        } else {
            int c = j - 64;
            float q2 = bf2f(query2[(size_t)(n*NECK + c)*HW + pix]);
            float kv = bilin32(k2small + (size_t)(n*NECK + c)*HWS, h, w);
            v = gamma * bf2f(value[(size_t)(n*NECK + c)*HW + pix]) * sigmoidf_(q2*kv);
        }
        ctx[j][p] = v;
    }

    int to = t >> 4, tp = t & 15;
    for (int oc=0; oc<4; ++oc){
        __syncthreads();
        #pragma unroll
        for (int i=0;i<32;i++){
            int e = i*256 + t;
            int ol = e >> 7, j = e & 127;
            wzt[j][ol] = wz[(size_t)(oc*64 + ol)*128 + j];
        }
        __syncthreads();
        float acc[4][4];
        #pragma unroll
        for (int i=0;i<4;i++){ acc[i][0]=0.f;acc[i][1]=0.f;acc[i][2]=0.f;acc[i][3]=0.f; }
        #pragma unroll 4
        for (int j=0;j<128;j++){
            float4 wv = *(const float4*)&wzt[j][to*4];
            float4 cv = *(const float4*)&ctx[j][tp*4];
            float wv4[4] = {wv.x,wv.y,wv.z,wv.w};
            #pragma unroll
            for (int i=0;i<4;i++){
                acc[i][0] = fmaf(wv4[i], cv.x, acc[i][0]);
                acc[i][1] = fmaf(wv4[i], cv.y, acc[i][1]);
                acc[i][2] = fmaf(wv4[i], cv.z, acc[i][2]);
                acc[i][3] = fmaf(wv4[i], cv.w, acc[i][3]);
            }
        }
        #pragma unroll
        for (int i=0;i<4;i++){
            int o = oc*64 + to*4 + i;
            *(float4*)&out[((size_t)n*CH + o)*HW + pix0 + tp*4] =
                make_float4(acc[i][0],acc[i][1],acc[i][2],acc[i][3]);
        }
    }
}

extern "C" void kernel_launch(void* const* d_in, const int* in_sizes, int n_in,
                              void* d_out, int out_size, void* d_ws, size_t ws_size,
                              hipStream_t stream) {
    const float* x0  = (const float*)d_in[0];
    const float* xo  = (const float*)d_in[1];
    const float* wq1 = (const float*)d_in[2];
    const float* s1  = (const float*)d_in[3];
    const float* b1  = (const float*)d_in[4];
    const float* wk1 = (const float*)d_in[5];
    const float* sk1 = (const float*)d_in[6];
    const float* bk1 = (const float*)d_in[7];
    const float* wv1 = (const float*)d_in[8];
    const float* wq2 = (const float*)d_in[9];
    const float* s2  = (const float*)d_in[10];
    const float* b2  = (const float*)d_in[11];
    const float* wk2 = (const float*)d_in[12];
    const float* sk2 = (const float*)d_in[13];
    const float* bk2 = (const float*)d_in[14];
    const float* wz  = (const float*)d_in[15];
    const float* alp = (const float*)d_in[16];
    const float* gam = (const float*)d_in[17];

    // workspace layout (all 16B-aligned): ~71.5 MB total
    ushort_t* value  = (ushort_t*)d_ws;          // 8*64*16384
    ushort_t* query  = value  + 8388608;
    ushort_t* query2 = query  + 8388608;
    float*    k1s    = (float*)(query2 + 8388608);   // 8*64*1024
    float*    k2s    = k1s + 524288;
    float*    g1     = k2s + 524288;             // 8*32*16
    float*    g2     = g1 + 4096;                // 8*32*64
    ushort_t* Wbig   = (ushort_t*)(g2 + 16384);  // 192*256
    ushort_t* XTc    = Wbig + 49152;             // 2*16384*256 bf16 chunk

    k_wprep<<<dim3(192), dim3(256), 0, stream>>>(wv1, wq1, wq2, Wbig);

    for (int c = 0; c < 4; ++c){
        k_transpose<<<dim3(2048), dim3(256), 0, stream>>>(
            x0 + (size_t)c*2*CH*HW, XTc);
        k_gemm_big<<<dim3(256), dim3(512), 0, stream>>>(
            XTc, Wbig, s1, b1, s2, b2, value, query, query2, 2*c);
    }

    k_conv_small<<<dim3(128), dim3(256), 0, stream>>>(xo, wk1, wk2, sk1, bk1, sk2, bk2,
                                                      k1s, k2s);
    k_gate1<<<dim3(256), dim3(256), 0, stream>>>(query, k1s, g1);
    k_gate2<<<dim3(256), dim3(256), 0, stream>>>(query, k1s, g2);
    k_final<<<dim3(2048), dim3(256), 0, stream>>>(value, query2, k2s, g1, g2, wz,
                                                  alp, gam, (float*)d_out);
}

// Round 3
// 262.882 us; speedup vs baseline: 2.4379x; 1.5798x over previous
//
#include <hip/hip_runtime.h>
#include <math.h>
#include <stdint.h>

#define N_    8
#define CH    256
#define CL    512
#define NECK  64
#define H_    128
#define W_    128
#define HW    16384
#define HWS   1024
#define EPSB  1e-5f
#define SC31  (31.0f/127.0f)

typedef unsigned short ushort_t;
typedef __attribute__((ext_vector_type(8))) short bf16x8;
typedef __attribute__((ext_vector_type(4))) float f32x4;

union bfpack { ushort_t u[8]; bf16x8 v; };

__device__ __forceinline__ float sigmoidf_(float x){ return 1.0f/(1.0f + __expf(-x)); }

__device__ __forceinline__ ushort_t f2bf(float x){
    union { float f; uint32_t u; } v; v.f = x;
    uint32_t r = (v.u + 0x7FFFu + ((v.u >> 16) & 1u)) >> 16;
    return (ushort_t)r;
}
__device__ __forceinline__ float bf2f(ushort_t b){
    union { uint32_t u; float f; } v; v.u = ((uint32_t)b) << 16;
    return v.f;
}

__device__ __forceinline__ void gload16(const void* g, void* l){
    __builtin_amdgcn_global_load_lds((const __attribute__((address_space(1))) void*)g,
                                     (__attribute__((address_space(3))) void*)l, 16, 0, 0);
}

// bilinear upsample (align_corners=True) from a 32x32 plane to 128x128 coords
__device__ __forceinline__ float bilin32(const float* __restrict__ src, int h, int w){
    float y = h * SC31, x = w * SC31;
    int y0 = (int)y, x0 = (int)x;
    int y1 = min(y0+1, 31), x1 = min(x0+1, 31);
    float fy = y - (float)y0, fx = x - (float)x0;
    float a = src[y0*32+x0], b = src[y0*32+x1];
    float c = src[y1*32+x0], d = src[y1*32+x1];
    float r0 = a + (b-a)*fx;
    float r1 = c + (d-c)*fx;
    return r0 + (r1-r0)*fy;
}

// ---------------- prep: pack big-conv weights [192][256] bf16 (rows: wv1, wq1, wq2)
__global__ __launch_bounds__(256) void k_wprep(
    const float* __restrict__ wv1, const float* __restrict__ wq1, const float* __restrict__ wq2,
    ushort_t* __restrict__ Wbig)
{
    int t = blockIdx.x*256 + threadIdx.x;          // 0..49151
    int o = t >> 8, c = t & 255;
    const float* w = (o < 64) ? (wv1 + (size_t)o*CH)
                   : (o < 128) ? (wq1 + (size_t)(o-64)*CH)
                               : (wq2 + (size_t)(o-128)*CH);
    Wbig[t] = f2bf(w[c]);
}

// ---------------- prep: pack final-conv weights wz [256][128] -> bf16
__global__ __launch_bounds__(256) void k_wzprep(
    const float* __restrict__ wz, ushort_t* __restrict__ Wzb)
{
    int t = blockIdx.x*256 + threadIdx.x;          // 0..32767
    Wzb[t] = f2bf(wz[t]);
}

// ---------------- prep: transpose+convert x[2img][256][16384] f32 -> XT[2img][16384][256] bf16
__global__ __launch_bounds__(256) void k_transpose(
    const float* __restrict__ src, ushort_t* __restrict__ dst)
{
    __shared__ ushort_t tile[64][66];
    int b = blockIdx.x;                 // 2 * 4 * 256 tiles
    int n = b >> 10;                    // 1024 tiles per image
    int r = b & 1023;
    int cb = (r >> 8) << 6;             // 4 c-tiles
    int pb = (r & 255) << 6;            // 256 p-tiles
    int t = threadIdx.x;
    const float* s = src + ((size_t)n*CH + cb)*HW + pb;
    int pl = t & 63, cl = t >> 6;       // cl 0..3
    #pragma unroll
    for (int i=0;i<16;i++){
        int c = cl*16 + i;
        tile[c][pl] = f2bf(s[(size_t)c*HW + pl]);
    }
    __syncthreads();
    ushort_t* d = dst + ((size_t)n*HW + pb)*CH + cb;
    int c2 = (t & 31)*2, pl2 = t >> 5;  // pl2 0..7
    #pragma unroll
    for (int i=0;i<8;i++){
        int p = pl2*8 + i;
        uint32_t v = (uint32_t)tile[c2][p] | ((uint32_t)tile[c2+1][p] << 16);
        *(uint32_t*)&d[(size_t)p*CH + c2] = v;
    }
}

// ---------------- K1: bf16 MFMA GEMM: C[192][pix] = Wbig[192][256] * XT^T ; BN=128, BK=64
__global__ __launch_bounds__(512) void k_gemm_big(
    const ushort_t* __restrict__ XT,   // [2][16384][256] bf16 chunk
    const ushort_t* __restrict__ Wb,   // [192][256] bf16
    const float* __restrict__ s1, const float* __restrict__ b1,
    const float* __restrict__ s2, const float* __restrict__ b2,
    ushort_t* __restrict__ value, ushort_t* __restrict__ query, ushort_t* __restrict__ query2,
    int nbase)
{
    __shared__ ushort_t At[192*64];    // 24KB (swizzled)
    __shared__ ushort_t Bt[128*64];    // 16KB (swizzled)
    int blk = blockIdx.x;
    int nl = blk >> 7;                 // local image 0..1
    int pix0 = (blk & 127) << 7;       // 128-pixel tile
    int t = threadIdx.x;
    int wid = t >> 6, lane = t & 63;
    int wm = wid >> 1, wn = wid & 1;   // 4(M) x 2(N) waves; wave tile 48 x 64

    f32x4 acc[3][4];
    #pragma unroll
    for (int m=0;m<3;m++)
        #pragma unroll
        for (int nn=0;nn<4;nn++) acc[m][nn] = (f32x4){0.f,0.f,0.f,0.f};

    const ushort_t* Xb = XT + ((size_t)nl*HW + pix0)*CH;
    for (int kt=0; kt<4; ++kt){
        int c0 = kt*64;
        // stage A: 1536 16B-chunks, 3 per thread; pre-swizzled source (rule #21)
        #pragma unroll
        for (int i=0;i<3;i++){
            int g = i*512 + t;
            int s = g ^ ((g>>3)&7);
            gload16(Wb + (size_t)(s>>3)*CH + c0 + (s&7)*8, (char*)At + g*16);
        }
        // stage B: 1024 chunks, 2 per thread
        #pragma unroll
        for (int i=0;i<2;i++){
            int g = i*512 + t;
            int s = g ^ ((g>>3)&7);
            gload16(Xb + (size_t)(s>>3)*CH + c0 + (s&7)*8, (char*)Bt + g*16);
        }
        __syncthreads();
        #pragma unroll
        for (int ks=0; ks<2; ++ks){
            bf16x8 a[3], b[4];
            #pragma unroll
            for (int m=0;m<3;m++){
                int row = wm*48 + m*16 + (lane&15);
                int off = (row*128 + ks*64 + (lane>>4)*16) ^ ((row&7)<<4);
                a[m] = *(const bf16x8*)((const char*)At + off);
            }
            #pragma unroll
            for (int nn=0;nn<4;nn++){
                int row = wn*64 + nn*16 + (lane&15);
                int off = (row*128 + ks*64 + (lane>>4)*16) ^ ((row&7)<<4);
                b[nn] = *(const bf16x8*)((const char*)Bt + off);
            }
            #pragma unroll
            for (int m=0;m<3;m++)
                #pragma unroll
                for (int nn=0;nn<4;nn++)
                    acc[m][nn] = __builtin_amdgcn_mfma_f32_16x16x32_bf16(a[m], b[nn], acc[m][nn], 0, 0, 0);
        }
        __syncthreads();
    }
    // epilogue: C/D layout col=lane&15 (pix), row=(lane>>4)*4+reg (o)
    int n = nbase + nl;
    float inv = rsqrtf(1.0f + EPSB);
    #pragma unroll
    for (int m=0;m<3;m++){
        int obase = wm*48 + m*16 + ((lane>>4)<<2);
        #pragma unroll
        for (int r=0;r<4;r++){
            int o = obase + r;
            int grp = o >> 6, oc = o & 63;
            float sc = 1.f, bb = 0.f;
            ushort_t* dst;
            if (grp == 0) dst = value;
            else if (grp == 1){ sc = s1[oc]*inv; bb = b1[oc]; dst = query; }
            else              { sc = s2[oc]*inv; bb = b2[oc]; dst = query2; }
            #pragma unroll
            for (int nn=0;nn<4;nn++){
                int pix = pix0 + wn*64 + nn*16 + (lane&15);
                float v = acc[m][nn][r];
                if (grp) v = fmaxf(fmaf(v, sc, bb), 0.f);
                dst[((size_t)(n*NECK + oc))*HW + pix] = f2bf(v);
            }
        }
    }
}

// ---------------- K2: small conv (fp32): other[8,512,1024] -> k1s/k2s fp32
__global__ __launch_bounds__(256) void k_conv_small(
    const float* __restrict__ x,
    const float* __restrict__ wk1, const float* __restrict__ wk2,
    const float* __restrict__ sk1, const float* __restrict__ bk1,
    const float* __restrict__ sk2, const float* __restrict__ bk2,
    float* __restrict__ k1small, float* __restrict__ k2small)
{
    __shared__ float xt[64][64];
    __shared__ float wt[64][132];
    int T = blockIdx.x;
    int n = T >> 4;
    int pix0 = (T & 15) * 64;
    int t = threadIdx.x;
    int to = t >> 4;
    int tp = t & 15;
    float acc[8][4];
    #pragma unroll
    for (int i=0;i<8;i++){ acc[i][0]=0.f;acc[i][1]=0.f;acc[i][2]=0.f;acc[i][3]=0.f; }

    const float* xb = x + (size_t)n*CL*HWS + pix0;
    for (int cc=0; cc<8; ++cc){
        #pragma unroll
        for (int i=0;i<16;i++){
            int e = i*256 + t;
            int c = e >> 6, p = e & 63;
            xt[c][p] = xb[(size_t)(cc*64 + c)*HWS + p];
        }
        #pragma unroll
        for (int i=0;i<32;i++){
            int e = i*256 + t;
            int o = e >> 6, c = e & 63;
            const float* wsrc = (o < 64) ? (wk1 + (size_t)o*CL) : (wk2 + (size_t)(o-64)*CL);
            wt[c][o] = wsrc[cc*64 + c];
        }
        __syncthreads();
        #pragma unroll 4
        for (int c=0;c<64;c++){
            float4 xv = *(const float4*)&xt[c][tp*4];
            const float4* wr = (const float4*)&wt[c][to*8];
            float4 wa = wr[0], wb = wr[1];
            float wv[8] = {wa.x,wa.y,wa.z,wa.w, wb.x,wb.y,wb.z,wb.w};
            #pragma unroll
            for (int i=0;i<8;i++){
                acc[i][0] = fmaf(wv[i], xv.x, acc[i][0]);
                acc[i][1] = fmaf(wv[i], xv.y, acc[i][1]);
                acc[i][2] = fmaf(wv[i], xv.z, acc[i][2]);
                acc[i][3] = fmaf(wv[i], xv.w, acc[i][3]);
            }
        }
        __syncthreads();
    }
    float inv = rsqrtf(1.0f + EPSB);
    #pragma unroll
    for (int i=0;i<8;i++){
        int o = to*8 + i;
        int g = o >> 6, oc = o & 63;
        float sc = (g ? sk2[oc] : sk1[oc]) * inv;
        float bb =  g ? bk2[oc] : bk1[oc];
        float4 r;
        r.x = fmaxf(fmaf(acc[i][0],sc,bb), 0.f);
        r.y = fmaxf(fmaf(acc[i][1],sc,bb), 0.f);
        r.z = fmaxf(fmaf(acc[i][2],sc,bb), 0.f);
        r.w = fmaxf(fmaf(acc[i][3],sc,bb), 0.f);
        float* dst = g ? k2small : k1small;
        *(float4*)&dst[(size_t)(n*NECK + oc)*HWS + pix0 + tp*4] = r;
    }
}

// ---------------- K3a: scale-1 gates (P=16 patches of 32x32), channels 0..31
__global__ __launch_bounds__(256) void k_gate1(
    const ushort_t* __restrict__ query, const float* __restrict__ k1small,
    float* __restrict__ gate1)
{
    __shared__ float ksm[1024];
    __shared__ float qt[16][260];
    __shared__ float kt[16][260];
    __shared__ float simM[16][17];
    int b = blockIdx.x;
    int n = b >> 5, c = b & 31;
    int t = threadIdx.x;
    const float* ks = k1small + (size_t)(n*NECK + c)*HWS;
    #pragma unroll
    for (int i=0;i<4;i++) ksm[i*256+t] = ks[i*256+t];
    const ushort_t* qb = query + (size_t)(n*NECK + c)*HW;
    int p_ = t >> 4, q_ = t & 15;
    float sim = 0.f;
    for (int lc=0; lc<4; ++lc){
        __syncthreads();
        #pragma unroll
        for (int i=0;i<16;i++){
            int p = i, s = t;
            int l = lc*256 + s;
            int ly = l >> 5, lx = l & 31;
            int h = (p>>2)*32 + ly, w = (p&3)*32 + lx;
            qt[p][s] = bf2f(qb[h*W_ + w]);
            kt[p][s] = bilin32(ksm, h, w);
        }
        __syncthreads();
        const float4* q4 = (const float4*)qt[p_];
        const float4* k4 = (const float4*)kt[q_];
        #pragma unroll 8
        for (int s4=0; s4<64; ++s4){
            float4 a = q4[s4], bb = k4[s4];
            sim += a.x*bb.x + a.y*bb.y + a.z*bb.z + a.w*bb.w;
        }
    }
    simM[p_][q_] = sigmoidf_(sim);
    __syncthreads();
    if (t < 16){
        float rs=0.f, cs=0.f;
        #pragma unroll
        for (int q=0;q<16;q++) rs += simM[t][q];
        #pragma unroll
        for (int p=0;p<16;p++) cs += simM[p][t];
        gate1[(size_t)(n*32 + c)*16 + t] = (rs + cs) * (1.0f/16.0f);
    }
}

// ---------------- K3b: scale-2 gates (P=64 patches of 16x16), channels 32..63
__global__ __launch_bounds__(256) void k_gate2(
    const ushort_t* __restrict__ query, const float* __restrict__ k1small,
    float* __restrict__ gate2)
{
    __shared__ float ksm[1024];
    __shared__ float qt[64][68];
    __shared__ float kt[64][68];
    __shared__ float simM[64][65];
    int b = blockIdx.x;
    int n = b >> 5, cl = b & 31, c = 32 + cl;
    int t = threadIdx.x;
    const float* ks = k1small + (size_t)(n*NECK + c)*HWS;
    #pragma unroll
    for (int i=0;i<4;i++) ksm[i*256+t] = ks[i*256+t];
    const ushort_t* qb = query + (size_t)(n*NECK + c)*HW;
    int p_ = t >> 2, qb_ = t & 3;
    float acc[16];
    #pragma unroll
    for (int j=0;j<16;j++) acc[j]=0.f;
    for (int lc=0; lc<4; ++lc){
        __syncthreads();
        #pragma unroll
        for (int i=0;i<16;i++){
            int e = i*256 + t;
            int p = e >> 6, s = e & 63;
            int l = lc*64 + s;
            int h = (p>>3)*16 + (l>>4), w = (p&7)*16 + (l&15);
            qt[p][s] = bf2f(qb[h*W_ + w]);
            kt[p][s] = bilin32(ksm, h, w);
        }
        __syncthreads();
        const float4* q4 = (const float4*)qt[p_];
        #pragma unroll 4
        for (int s4=0; s4<16; ++s4){
            float4 a = q4[s4];
            #pragma unroll
            for (int j=0;j<16;j++){
                float4 bb = ((const float4*)kt[qb_ + 4*j])[s4];
                acc[j] += a.x*bb.x + a.y*bb.y + a.z*bb.z + a.w*bb.w;
            }
        }
    }
    #pragma unroll
    for (int j=0;j<16;j++) simM[p_][qb_ + 4*j] = sigmoidf_(acc[j]);
    __syncthreads();
    if (t < 64){
        float rs=0.f, cs=0.f;
        for (int q=0;q<64;q++) rs += simM[t][q];
        for (int p=0;p<64;p++) cs += simM[p][t];
        gate2[(size_t)(n*32 + cl)*64 + t] = (rs + cs) * (1.0f/64.0f);
    }
}

// ---------------- K4: context build + final conv via bf16 MFMA
// block = 1 image-row (128 px), 512 threads (8 waves: 4M x 2N), BM=256, BN=128, K=128
__global__ __launch_bounds__(512) void k_final_mfma(
    const ushort_t* __restrict__ value, const ushort_t* __restrict__ query2,
    const float* __restrict__ k2small,
    const float* __restrict__ gate1, const float* __restrict__ gate2,
    const ushort_t* __restrict__ Wzb,   // [256][128] bf16
    const float* __restrict__ alpha_p, const float* __restrict__ gamma_p,
    float* __restrict__ out)
{
    __shared__ ushort_t Wt[256*128];   // 64KB swizzled A
    __shared__ ushort_t Ct[128*128];   // 32KB swizzled B (ctx)
    __shared__ float g1s[512];
    __shared__ float g2s[2048];
    __shared__ float k2r[2][64*32];    // 16KB: rows y0,y1 for all 64 ch
    int blk = blockIdx.x;
    int n = blk >> 7, h = blk & 127;
    int pix0 = h << 7;
    int t = threadIdx.x;
    int lane = t & 63;
    int wid = t >> 6;
    int wm = wid >> 1, wn = wid & 1;

    // issue A staging first so it overlaps the ctx build (swizzled via source, rule #21)
    #pragma unroll
    for (int i=0;i<8;i++){
        int g = i*512 + t;
        int s = (g & ~15) | ((g & 15) ^ ((g >> 4) & 7));
        gload16(Wzb + s*8, (char*)Wt + g*16);
    }

    float alpha = alpha_p[0], gamma = gamma_p[0];
    g1s[t & 511] = gate1[(size_t)n*512 + (t & 511)];
    #pragma unroll
    for (int i=0;i<4;i++) g2s[i*512 + t] = gate2[(size_t)n*2048 + i*512 + t];

    float yf = h * SC31;
    int y0 = (int)yf, y1 = min(y0+1, 31);
    float fy = yf - (float)y0;
    #pragma unroll
    for (int i=0;i<8;i++){
        int e = i*512 + t;              // 4096
        int buf = e >> 11, c = (e >> 5) & 63, xx = e & 31;
        k2r[buf][c*32 + xx] = k2small[((size_t)n*NECK + c)*HWS + (buf ? y1 : y0)*32 + xx];
    }
    __syncthreads();

    // ctx build: thread -> (px, 32-channel group); write bf16x8 chunks swizzled
    int px = t & 127, chg = t >> 7;
    int w = px;
    float xf = w * SC31;
    int x0 = (int)xf, x1 = min(x0+1, 31);
    float fx = xf - (float)x0;
    int patch1 = (h>>5)*4 + (w>>5);
    int patch2 = (h>>4)*8 + (w>>4);
    int ch0 = chg*32;
    const size_t vbase = (size_t)n*NECK*HW + pix0 + px;
    #pragma unroll
    for (int j=0;j<4;j++){
        bfpack pk;
        #pragma unroll
        for (int i=0;i<8;i++){
            int ch = ch0 + j*8 + i;
            float v;
            if (chg < 2){
                float g = (ch < 32) ? g1s[ch*16 + patch1] : g2s[(ch-32)*64 + patch2];
                v = alpha * g * bf2f(value[vbase + (size_t)ch*HW]);
            } else {
                int c = ch - 64;
                float vv = bf2f(value[vbase + (size_t)c*HW]);
                float q2 = bf2f(query2[vbase + (size_t)c*HW]);
                float r0 = k2r[0][c*32+x0]; r0 += (k2r[0][c*32+x1] - r0)*fx;
                float r1 = k2r[1][c*32+x0]; r1 += (k2r[1][c*32+x1] - r1)*fx;
                float kv = r0 + (r1 - r0)*fy;
                v = gamma * vv * sigmoidf_(q2*kv);
            }
            pk.u[i] = f2bf(v);
        }
        int off = (px*256 + ch0*2 + j*16) ^ ((px&7)<<4);
        *(bf16x8*)((char*)Ct + off) = pk.v;
    }
    __syncthreads();

    // MFMA: wave tile 64(o) x 64(px), K=128 in 4 steps
    f32x4 acc[4][4];
    #pragma unroll
    for (int m=0;m<4;m++)
        #pragma unroll
        for (int nn=0;nn<4;nn++) acc[m][nn] = (f32x4){0.f,0.f,0.f,0.f};
    #pragma unroll
    for (int ks=0; ks<4; ++ks){
        bf16x8 a[4], b[4];
        #pragma unroll
        for (int m=0;m<4;m++){
            int row = wm*64 + m*16 + (lane&15);
            int off = (row*256 + ks*64 + (lane>>4)*16) ^ ((row&7)<<4);
            a[m] = *(const bf16x8*)((const char*)Wt + off);
        }
        #pragma unroll
        for (int nn=0;nn<4;nn++){
            int row = wn*64 + nn*16 + (lane&15);
            int off = (row*256 + ks*64 + (lane>>4)*16) ^ ((row&7)<<4);
            b[nn] = *(const bf16x8*)((const char*)Ct + off);
        }
        #pragma unroll
        for (int m=0;m<4;m++)
            #pragma unroll
            for (int nn=0;nn<4;nn++)
                acc[m][nn] = __builtin_amdgcn_mfma_f32_16x16x32_bf16(a[m], b[nn], acc[m][nn], 0, 0, 0);
    }

    // epilogue: o = row, px = col
    #pragma unroll
    for (int m=0;m<4;m++){
        int obase = wm*64 + m*16 + ((lane>>4)<<2);
        #pragma unroll
        for (int r=0;r<4;r++){
            int o = obase + r;
            float* dst = out + ((size_t)(n*CH + o))*HW + pix0 + wn*64 + (lane&15);
            #pragma unroll
            for (int nn=0;nn<4;nn++)
                dst[nn*16] = acc[m][nn][r];
        }
    }
}

extern "C" void kernel_launch(void* const* d_in, const int* in_sizes, int n_in,
                              void* d_out, int out_size, void* d_ws, size_t ws_size,
                              hipStream_t stream) {
    const float* x0  = (const float*)d_in[0];
    const float* xo  = (const float*)d_in[1];
    const float* wq1 = (const float*)d_in[2];
    const float* s1  = (const float*)d_in[3];
    const float* b1  = (const float*)d_in[4];
    const float* wk1 = (const float*)d_in[5];
    const float* sk1 = (const float*)d_in[6];
    const float* bk1 = (const float*)d_in[7];
    const float* wv1 = (const float*)d_in[8];
    const float* wq2 = (const float*)d_in[9];
    const float* s2  = (const float*)d_in[10];
    const float* b2  = (const float*)d_in[11];
    const float* wk2 = (const float*)d_in[12];
    const float* sk2 = (const float*)d_in[13];
    const float* bk2 = (const float*)d_in[14];
    const float* wz  = (const float*)d_in[15];
    const float* alp = (const float*)d_in[16];
    const float* gam = (const float*)d_in[17];

    // workspace layout (all 16B-aligned): ~71.6 MB total
    ushort_t* value  = (ushort_t*)d_ws;          // 8*64*16384
    ushort_t* query  = value  + 8388608;
    ushort_t* query2 = query  + 8388608;
    float*    k1s    = (float*)(query2 + 8388608);   // 8*64*1024
    float*    k2s    = k1s + 524288;
    float*    g1     = k2s + 524288;             // 8*32*16
    float*    g2     = g1 + 4096;                // 8*32*64
    ushort_t* Wbig   = (ushort_t*)(g2 + 16384);  // 192*256
    ushort_t* XTc    = Wbig + 49152;             // 2*16384*256 bf16 chunk
    ushort_t* Wzb    = XTc + 8388608;            // 256*128

    k_wprep <<<dim3(192), dim3(256), 0, stream>>>(wv1, wq1, wq2, Wbig);
    k_wzprep<<<dim3(128), dim3(256), 0, stream>>>(wz, Wzb);

    for (int c = 0; c < 4; ++c){
        k_transpose<<<dim3(2048), dim3(256), 0, stream>>>(
            x0 + (size_t)c*2*CH*HW, XTc);
        k_gemm_big<<<dim3(256), dim3(512), 0, stream>>>(
            XTc, Wbig, s1, b1, s2, b2, value, query, query2, 2*c);
    }

    k_conv_small<<<dim3(128), dim3(256), 0, stream>>>(xo, wk1, wk2, sk1, bk1, sk2, bk2,
                                                      k1s, k2s);
    k_gate1<<<dim3(256), dim3(256), 0, stream>>>(query, k1s, g1);
    k_gate2<<<dim3(256), dim3(256), 0, stream>>>(query, k1s, g2);
    k_final_mfma<<<dim3(1024), dim3(512), 0, stream>>>(value, query2, k2s, g1, g2, Wzb,
                                                       alp, gam, (float*)d_out);
}

// Round 4
// 202.358 us; speedup vs baseline: 3.1671x; 1.2991x over previous
//
#include <hip/hip_runtime.h>
#include <math.h>
#include <stdint.h>

#define N_    8
#define CH    256
#define CL    512
#define NECK  64
#define H_    128
#define W_    128
#define HW    16384
#define HWS   1024
#define EPSB  1e-5f
#define SC31  (31.0f/127.0f)

typedef unsigned short ushort_t;
typedef __attribute__((ext_vector_type(8))) short bf16x8;
typedef __attribute__((ext_vector_type(4))) float f32x4;

union bfpack { ushort_t u[8]; bf16x8 v; };

__device__ __forceinline__ float sigmoidf_(float x){ return 1.0f/(1.0f + __expf(-x)); }

__device__ __forceinline__ ushort_t f2bf(float x){
    union { float f; uint32_t u; } v; v.f = x;
    uint32_t r = (v.u + 0x7FFFu + ((v.u >> 16) & 1u)) >> 16;
    return (ushort_t)r;
}
__device__ __forceinline__ float bf2f(ushort_t b){
    union { uint32_t u; float f; } v; v.u = ((uint32_t)b) << 16;
    return v.f;
}

__device__ __forceinline__ void gload16(const void* g, void* l){
    __builtin_amdgcn_global_load_lds((const __attribute__((address_space(1))) void*)g,
                                     (__attribute__((address_space(3))) void*)l, 16, 0, 0);
}

// bilinear upsample (align_corners=True) from a 32x32 plane to 128x128 coords
__device__ __forceinline__ float bilin32(const float* __restrict__ src, int h, int w){
    float y = h * SC31, x = w * SC31;
    int y0 = (int)y, x0 = (int)x;
    int y1 = min(y0+1, 31), x1 = min(x0+1, 31);
    float fy = y - (float)y0, fx = x - (float)x0;
    float a = src[y0*32+x0], b = src[y0*32+x1];
    float c = src[y1*32+x0], d = src[y1*32+x1];
    float r0 = a + (b-a)*fx;
    float r1 = c + (d-c)*fx;
    return r0 + (r1-r0)*fy;
}

// ---------------- prep: pack big-conv weights [192][256] and wz [256][128] to bf16
__global__ __launch_bounds__(256) void k_prep(
    const float* __restrict__ wv1, const float* __restrict__ wq1, const float* __restrict__ wq2,
    const float* __restrict__ wz,
    ushort_t* __restrict__ Wbig, ushort_t* __restrict__ Wzb)
{
    int t = blockIdx.x*256 + threadIdx.x;          // 0..81919
    if (t < 49152){
        int o = t >> 8, c = t & 255;
        const float* w = (o < 64) ? (wv1 + (size_t)o*CH)
                       : (o < 128) ? (wq1 + (size_t)(o-64)*CH)
                                   : (wq2 + (size_t)(o-128)*CH);
        Wbig[t] = f2bf(w[c]);
    } else {
        int i = t - 49152;                          // 0..32767
        Wzb[i] = f2bf(wz[i]);
    }
}

// ---------------- K1: fused transpose + bf16 MFMA GEMM over ALL 8 images
// C[192][pix] = Wbig[192][256] * X[256][pix]; BM=192, BN=128, BK=64, 8 waves (4M x 2N)
__global__ __launch_bounds__(512) void k_gemm_big(
    const float* __restrict__ x,       // [8][256][16384] f32
    const ushort_t* __restrict__ Wb,   // [192][256] bf16
    const float* __restrict__ s1, const float* __restrict__ b1,
    const float* __restrict__ s2, const float* __restrict__ b2,
    ushort_t* __restrict__ value, ushort_t* __restrict__ query, ushort_t* __restrict__ query2)
{
    __shared__ ushort_t At[192*64];    // 24KB (swizzled)
    __shared__ ushort_t Bt[128*64];    // 16KB (swizzled)
    int blk = blockIdx.x;              // 1024 = 8 img * 128 px-tiles
    int n = blk >> 7;
    int pix0 = (blk & 127) << 7;       // 128-pixel tile
    int t = threadIdx.x;
    int lane = t & 63;
    int w8 = t >> 6;                   // wave 0..7
    int wm = w8 >> 1, wn = w8 & 1;     // 4(M) x 2(N); wave tile 48 x 64

    f32x4 acc[3][4];
    #pragma unroll
    for (int m=0;m<3;m++)
        #pragma unroll
        for (int nn=0;nn<4;nn++) acc[m][nn] = (f32x4){0.f,0.f,0.f,0.f};

    const float* xb = x + (size_t)n*CH*HW + pix0;
    for (int kt=0; kt<4; ++kt){
        int c0 = kt*64;
        // stage A (async gload_lds): 1536 16B-chunks, 3/thread; pre-swizzled source
        #pragma unroll
        for (int i=0;i<3;i++){
            int g = i*512 + t;
            int s = g ^ ((g>>3)&7);
            gload16(Wb + (size_t)(s>>3)*CH + c0 + (s&7)*8, (char*)At + g*16);
        }
        // stage B via registers (fused transpose+convert):
        // thread: 8 channels (c_local = 8*w8+j) x 2 px (lane, lane+64); coalesced 256B rows
        const float* xc = xb + (size_t)(c0 + 8*w8)*HW;
        float va[8], vb[8];
        #pragma unroll
        for (int j=0;j<8;j++){
            va[j] = xc[(size_t)j*HW + lane];
            vb[j] = xc[(size_t)j*HW + 64 + lane];
        }
        uint32_t pa[4], pb[4];
        #pragma unroll
        for (int j=0;j<4;j++){
            pa[j] = (uint32_t)f2bf(va[2*j]) | ((uint32_t)f2bf(va[2*j+1]) << 16);
            pb[j] = (uint32_t)f2bf(vb[2*j]) | ((uint32_t)f2bf(vb[2*j+1]) << 16);
        }
        int c2 = (8*w8)*2;             // byte column in 128B row
        int offA = (lane*128 + c2) ^ ((lane&7)<<4);
        int offB = ((lane+64)*128 + c2) ^ ((lane&7)<<4);   // (lane+64)&7 == lane&7
        *(uint4*)((char*)Bt + offA) = make_uint4(pa[0],pa[1],pa[2],pa[3]);
        *(uint4*)((char*)Bt + offB) = make_uint4(pb[0],pb[1],pb[2],pb[3]);
        __syncthreads();
        #pragma unroll
        for (int ks=0; ks<2; ++ks){
            bf16x8 a[3], b[4];
            #pragma unroll
            for (int m=0;m<3;m++){
                int row = wm*48 + m*16 + (lane&15);
                int off = (row*128 + ks*64 + (lane>>4)*16) ^ ((row&7)<<4);
                a[m] = *(const bf16x8*)((const char*)At + off);
            }
            #pragma unroll
            for (int nn=0;nn<4;nn++){
                int row = wn*64 + nn*16 + (lane&15);
                int off = (row*128 + ks*64 + (lane>>4)*16) ^ ((row&7)<<4);
                b[nn] = *(const bf16x8*)((const char*)Bt + off);
            }
            #pragma unroll
            for (int m=0;m<3;m++)
                #pragma unroll
                for (int nn=0;nn<4;nn++)
                    acc[m][nn] = __builtin_amdgcn_mfma_f32_16x16x32_bf16(a[m], b[nn], acc[m][nn], 0, 0, 0);
        }
        __syncthreads();
    }
    // epilogue: C/D layout col=lane&15 (pix), row=(lane>>4)*4+reg (o)
    float inv = rsqrtf(1.0f + EPSB);
    #pragma unroll
    for (int m=0;m<3;m++){
        int obase = wm*48 + m*16 + ((lane>>4)<<2);
        #pragma unroll
        for (int r=0;r<4;r++){
            int o = obase + r;
            int grp = o >> 6, oc = o & 63;
            float sc = 1.f, bb = 0.f;
            ushort_t* dst;
            if (grp == 0) dst = value;
            else if (grp == 1){ sc = s1[oc]*inv; bb = b1[oc]; dst = query; }
            else              { sc = s2[oc]*inv; bb = b2[oc]; dst = query2; }
            #pragma unroll
            for (int nn=0;nn<4;nn++){
                int pix = pix0 + wn*64 + nn*16 + (lane&15);
                float v = acc[m][nn][r];
                if (grp) v = fmaxf(fmaf(v, sc, bb), 0.f);
                dst[((size_t)(n*NECK + oc))*HW + pix] = f2bf(v);
            }
        }
    }
}

// ---------------- K2: small conv (fp32): other[8,512,1024] -> k1s/k2s fp32
__global__ __launch_bounds__(256) void k_conv_small(
    const float* __restrict__ x,
    const float* __restrict__ wk1, const float* __restrict__ wk2,
    const float* __restrict__ sk1, const float* __restrict__ bk1,
    const float* __restrict__ sk2, const float* __restrict__ bk2,
    float* __restrict__ k1small, float* __restrict__ k2small)
{
    __shared__ float xt[64][64];
    __shared__ float wt[64][132];
    int T = blockIdx.x;
    int n = T >> 4;
    int pix0 = (T & 15) * 64;
    int t = threadIdx.x;
    int to = t >> 4;
    int tp = t & 15;
    float acc[8][4];
    #pragma unroll
    for (int i=0;i<8;i++){ acc[i][0]=0.f;acc[i][1]=0.f;acc[i][2]=0.f;acc[i][3]=0.f; }

    const float* xb = x + (size_t)n*CL*HWS + pix0;
    for (int cc=0; cc<8; ++cc){
        #pragma unroll
        for (int i=0;i<16;i++){
            int e = i*256 + t;
            int c = e >> 6, p = e & 63;
            xt[c][p] = xb[(size_t)(cc*64 + c)*HWS + p];
        }
        #pragma unroll
        for (int i=0;i<32;i++){
            int e = i*256 + t;
            int o = e >> 6, c = e & 63;
            const float* wsrc = (o < 64) ? (wk1 + (size_t)o*CL) : (wk2 + (size_t)(o-64)*CL);
            wt[c][o] = wsrc[cc*64 + c];
        }
        __syncthreads();
        #pragma unroll 4
        for (int c=0;c<64;c++){
            float4 xv = *(const float4*)&xt[c][tp*4];
            const float4* wr = (const float4*)&wt[c][to*8];
            float4 wa = wr[0], wb = wr[1];
            float wv[8] = {wa.x,wa.y,wa.z,wa.w, wb.x,wb.y,wb.z,wb.w};
            #pragma unroll
            for (int i=0;i<8;i++){
                acc[i][0] = fmaf(wv[i], xv.x, acc[i][0]);
                acc[i][1] = fmaf(wv[i], xv.y, acc[i][1]);
                acc[i][2] = fmaf(wv[i], xv.z, acc[i][2]);
                acc[i][3] = fmaf(wv[i], xv.w, acc[i][3]);
            }
        }
        __syncthreads();
    }
    float inv = rsqrtf(1.0f + EPSB);
    #pragma unroll
    for (int i=0;i<8;i++){
        int o = to*8 + i;
        int g = o >> 6, oc = o & 63;
        float sc = (g ? sk2[oc] : sk1[oc]) * inv;
        float bb =  g ? bk2[oc] : bk1[oc];
        float4 r;
        r.x = fmaxf(fmaf(acc[i][0],sc,bb), 0.f);
        r.y = fmaxf(fmaf(acc[i][1],sc,bb), 0.f);
        r.z = fmaxf(fmaf(acc[i][2],sc,bb), 0.f);
        r.w = fmaxf(fmaf(acc[i][3],sc,bb), 0.f);
        float* dst = g ? k2small : k1small;
        *(float4*)&dst[(size_t)(n*NECK + oc)*HWS + pix0 + tp*4] = r;
    }
}

// ---------------- K3: merged gate kernel; blocks 0..255 = scale-1, 256..511 = scale-2
__global__ __launch_bounds__(256) void k_gates(
    const ushort_t* __restrict__ query, const float* __restrict__ k1small,
    float* __restrict__ gate1, float* __restrict__ gate2)
{
    __shared__ float smem[13888];      // 55.5KB carved union
    int bid = blockIdx.x;
    int t = threadIdx.x;
    if (bid < 256){
        // scale-1: P=16 patches of 32x32, channels 0..31
        float* ksm = smem;                                  // 1024
        float (*qt)[260]  = (float(*)[260])(smem + 1024);   // 16*260 = 4160
        float (*kt)[260]  = (float(*)[260])(smem + 5184);   // 4160
        float (*simM)[17] = (float(*)[17]) (smem + 9344);   // 272
        int n = bid >> 5, c = bid & 31;
        const float* ks = k1small + (size_t)(n*NECK + c)*HWS;
        #pragma unroll
        for (int i=0;i<4;i++) ksm[i*256+t] = ks[i*256+t];
        const ushort_t* qb = query + (size_t)(n*NECK + c)*HW;
        int p_ = t >> 4, q_ = t & 15;
        float sim = 0.f;
        for (int lc=0; lc<4; ++lc){
            __syncthreads();
            #pragma unroll
            for (int i=0;i<16;i++){
                int p = i, s = t;
                int l = lc*256 + s;
                int ly = l >> 5, lx = l & 31;
                int h = (p>>2)*32 + ly, w = (p&3)*32 + lx;
                qt[p][s] = bf2f(qb[h*W_ + w]);
                kt[p][s] = bilin32(ksm, h, w);
            }
            __syncthreads();
            const float4* q4 = (const float4*)qt[p_];
            const float4* k4 = (const float4*)kt[q_];
            #pragma unroll 8
            for (int s4=0; s4<64; ++s4){
                float4 a = q4[s4], bb = k4[s4];
                sim += a.x*bb.x + a.y*bb.y + a.z*bb.z + a.w*bb.w;
            }
        }
        simM[p_][q_] = sigmoidf_(sim);
        __syncthreads();
        if (t < 16){
            float rs=0.f, cs=0.f;
            #pragma unroll
            for (int q=0;q<16;q++) rs += simM[t][q];
            #pragma unroll
            for (int p=0;p<16;p++) cs += simM[p][t];
            gate1[(size_t)(n*32 + c)*16 + t] = (rs + cs) * (1.0f/16.0f);
        }
    } else {
        // scale-2: P=64 patches of 16x16, channels 32..63
        float* ksm = smem;                                  // 1024
        float (*qt)[68]   = (float(*)[68])(smem + 1024);    // 64*68 = 4352
        float (*kt)[68]   = (float(*)[68])(smem + 5376);    // 4352
        float (*simM)[65] = (float(*)[65])(smem + 9728);    // 4160
        int b = bid - 256;
        int n = b >> 5, cl = b & 31, c = 32 + cl;
        const float* ks = k1small + (size_t)(n*NECK + c)*HWS;
        #pragma unroll
        for (int i=0;i<4;i++) ksm[i*256+t] = ks[i*256+t];
        const ushort_t* qb = query + (size_t)(n*NECK + c)*HW;
        int p_ = t >> 2, qb_ = t & 3;
        float acc[16];
        #pragma unroll
        for (int j=0;j<16;j++) acc[j]=0.f;
        for (int lc=0; lc<4; ++lc){
            __syncthreads();
            #pragma unroll
            for (int i=0;i<16;i++){
                int e = i*256 + t;
                int p = e >> 6, s = e & 63;
                int l = lc*64 + s;
                int h = (p>>3)*16 + (l>>4), w = (p&7)*16 + (l&15);
                qt[p][s] = bf2f(qb[h*W_ + w]);
                kt[p][s] = bilin32(ksm, h, w);
            }
            __syncthreads();
            const float4* q4 = (const float4*)qt[p_];
            #pragma unroll 4
            for (int s4=0; s4<16; ++s4){
                float4 a = q4[s4];
                #pragma unroll
                for (int j=0;j<16;j++){
                    float4 bb = ((const float4*)kt[qb_ + 4*j])[s4];
                    acc[j] += a.x*bb.x + a.y*bb.y + a.z*bb.z + a.w*bb.w;
                }
            }
        }
        #pragma unroll
        for (int j=0;j<16;j++) simM[p_][qb_ + 4*j] = sigmoidf_(acc[j]);
        __syncthreads();
        if (t < 64){
            float rs=0.f, cs=0.f;
            for (int q=0;q<64;q++) rs += simM[t][q];
            for (int p=0;p<64;p++) cs += simM[p][t];
            gate2[(size_t)(n*32 + cl)*64 + t] = (rs + cs) * (1.0f/64.0f);
        }
    }
}

// ---------------- K4: context build + final conv via bf16 MFMA
// block = 1 image-row (128 px), 512 threads (8 waves: 4M x 2N), BM=256, BN=128, K=128
__global__ __launch_bounds__(512) void k_final_mfma(
    const ushort_t* __restrict__ value, const ushort_t* __restrict__ query2,
    const float* __restrict__ k2small,
    const float* __restrict__ gate1, const float* __restrict__ gate2,
    const ushort_t* __restrict__ Wzb,   // [256][128] bf16
    const float* __restrict__ alpha_p, const float* __restrict__ gamma_p,
    float* __restrict__ out)
{
    __shared__ ushort_t Wt[256*128];   // 64KB swizzled A
    __shared__ ushort_t Ct[128*128];   // 32KB swizzled B (ctx)
    __shared__ float g1s[512];
    __shared__ float g2s[2048];
    __shared__ float k2r[2][64*32];    // 16KB: rows y0,y1 for all 64 ch
    int blk = blockIdx.x;
    int n = blk >> 7, h = blk & 127;
    int pix0 = h << 7;
    int t = threadIdx.x;
    int lane = t & 63;
    int wid = t >> 6;
    int wm = wid >> 1, wn = wid & 1;

    // issue A staging first so it overlaps the ctx build (swizzled via source, rule #21)
    #pragma unroll
    for (int i=0;i<8;i++){
        int g = i*512 + t;
        int s = (g & ~15) | ((g & 15) ^ ((g >> 4) & 7));
        gload16(Wzb + s*8, (char*)Wt + g*16);
    }

    float alpha = alpha_p[0], gamma = gamma_p[0];
    g1s[t & 511] = gate1[(size_t)n*512 + (t & 511)];
    #pragma unroll
    for (int i=0;i<4;i++) g2s[i*512 + t] = gate2[(size_t)n*2048 + i*512 + t];

    float yf = h * SC31;
    int y0 = (int)yf, y1 = min(y0+1, 31);
    float fy = yf - (float)y0;
    #pragma unroll
    for (int i=0;i<8;i++){
        int e = i*512 + t;              // 4096
        int buf = e >> 11, c = (e >> 5) & 63, xx = e & 31;
        k2r[buf][c*32 + xx] = k2small[((size_t)n*NECK + c)*HWS + (buf ? y1 : y0)*32 + xx];
    }
    __syncthreads();

    // ctx build: thread -> (px, 32-channel group); write bf16x8 chunks swizzled
    int px = t & 127, chg = t >> 7;
    int w = px;
    float xf = w * SC31;
    int x0 = (int)xf, x1 = min(x0+1, 31);
    float fx = xf - (float)x0;
    int patch1 = (h>>5)*4 + (w>>5);
    int patch2 = (h>>4)*8 + (w>>4);
    int ch0 = chg*32;
    const size_t vbase = (size_t)n*NECK*HW + pix0 + px;
    #pragma unroll
    for (int j=0;j<4;j++){
        bfpack pk;
        #pragma unroll
        for (int i=0;i<8;i++){
            int ch = ch0 + j*8 + i;
            float v;
            if (chg < 2){
                float g = (ch < 32) ? g1s[ch*16 + patch1] : g2s[(ch-32)*64 + patch2];
                v = alpha * g * bf2f(value[vbase + (size_t)ch*HW]);
            } else {
                int c = ch - 64;
                float vv = bf2f(value[vbase + (size_t)c*HW]);
                float q2 = bf2f(query2[vbase + (size_t)c*HW]);
                float r0 = k2r[0][c*32+x0]; r0 += (k2r[0][c*32+x1] - r0)*fx;
                float r1 = k2r[1][c*32+x0]; r1 += (k2r[1][c*32+x1] - r1)*fx;
                float kv = r0 + (r1 - r0)*fy;
                v = gamma * vv * sigmoidf_(q2*kv);
            }
            pk.u[i] = f2bf(v);
        }
        int off = (px*256 + ch0*2 + j*16) ^ ((px&7)<<4);
        *(bf16x8*)((char*)Ct + off) = pk.v;
    }
    __syncthreads();

    // MFMA: wave tile 64(o) x 64(px), K=128 in 4 steps
    f32x4 acc[4][4];
    #pragma unroll
    for (int m=0;m<4;m++)
        #pragma unroll
        for (int nn=0;nn<4;nn++) acc[m][nn] = (f32x4){0.f,0.f,0.f,0.f};
    #pragma unroll
    for (int ks=0; ks<4; ++ks){
        bf16x8 a[4], b[4];
        #pragma unroll
        for (int m=0;m<4;m++){
            int row = wm*64 + m*16 + (lane&15);
            int off = (row*256 + ks*64 + (lane>>4)*16) ^ ((row&7)<<4);
            a[m] = *(const bf16x8*)((const char*)Wt + off);
        }
        #pragma unroll
        for (int nn=0;nn<4;nn++){
            int row = wn*64 + nn*16 + (lane&15);
            int off = (row*256 + ks*64 + (lane>>4)*16) ^ ((row&7)<<4);
            b[nn] = *(const bf16x8*)((const char*)Ct + off);
        }
        #pragma unroll
        for (int m=0;m<4;m++)
            #pragma unroll
            for (int nn=0;nn<4;nn++)
                acc[m][nn] = __builtin_amdgcn_mfma_f32_16x16x32_bf16(a[m], b[nn], acc[m][nn], 0, 0, 0);
    }

    // epilogue: o = row, px = col
    #pragma unroll
    for (int m=0;m<4;m++){
        int obase = wm*64 + m*16 + ((lane>>4)<<2);
        #pragma unroll
        for (int r=0;r<4;r++){
            int o = obase + r;
            float* dst = out + ((size_t)(n*CH + o))*HW + pix0 + wn*64 + (lane&15);
            #pragma unroll
            for (int nn=0;nn<4;nn++)
                dst[nn*16] = acc[m][nn][r];
        }
    }
}

extern "C" void kernel_launch(void* const* d_in, const int* in_sizes, int n_in,
                              void* d_out, int out_size, void* d_ws, size_t ws_size,
                              hipStream_t stream) {
    const float* x0  = (const float*)d_in[0];
    const float* xo  = (const float*)d_in[1];
    const float* wq1 = (const float*)d_in[2];
    const float* s1  = (const float*)d_in[3];
    const float* b1  = (const float*)d_in[4];
    const float* wk1 = (const float*)d_in[5];
    const float* sk1 = (const float*)d_in[6];
    const float* bk1 = (const float*)d_in[7];
    const float* wv1 = (const float*)d_in[8];
    const float* wq2 = (const float*)d_in[9];
    const float* s2  = (const float*)d_in[10];
    const float* b2  = (const float*)d_in[11];
    const float* wk2 = (const float*)d_in[12];
    const float* sk2 = (const float*)d_in[13];
    const float* bk2 = (const float*)d_in[14];
    const float* wz  = (const float*)d_in[15];
    const float* alp = (const float*)d_in[16];
    const float* gam = (const float*)d_in[17];

    // workspace layout (all 16B-aligned): ~55 MB total
    ushort_t* value  = (ushort_t*)d_ws;          // 8*64*16384
    ushort_t* query  = value  + 8388608;
    ushort_t* query2 = query  + 8388608;
    float*    k1s    = (float*)(query2 + 8388608);   // 8*64*1024
    float*    k2s    = k1s + 524288;
    float*    g1     = k2s + 524288;             // 8*32*16
    float*    g2     = g1 + 4096;                // 8*32*64
    ushort_t* Wbig   = (ushort_t*)(g2 + 16384);  // 192*256
    ushort_t* Wzb    = Wbig + 49152;             // 256*128

    k_prep<<<dim3(320), dim3(256), 0, stream>>>(wv1, wq1, wq2, wz, Wbig, Wzb);
    k_gemm_big<<<dim3(1024), dim3(512), 0, stream>>>(
        x0, Wbig, s1, b1, s2, b2, value, query, query2);
    k_conv_small<<<dim3(128), dim3(256), 0, stream>>>(xo, wk1, wk2, sk1, bk1, sk2, bk2,
                                                      k1s, k2s);
    k_gates<<<dim3(512), dim3(256), 0, stream>>>(query, k1s, g1, g2);
    k_final_mfma<<<dim3(1024), dim3(512), 0, stream>>>(value, query2, k2s, g1, g2, Wzb,
                                                       alp, gam, (float*)d_out);
}

// Round 5
// 163.959 us; speedup vs baseline: 3.9088x; 1.2342x over previous
//
#include <hip/hip_runtime.h>
#include <math.h>
#include <stdint.h>

#define N_    8
#define CH    256
#define CL    512
#define NECK  64
#define H_    128
#define W_    128
#define HW    16384
#define HWS   1024
#define EPSB  1e-5f
#define SC31  (31.0f/127.0f)

typedef unsigned short ushort_t;
typedef __attribute__((ext_vector_type(8))) short bf16x8;
typedef __attribute__((ext_vector_type(4))) float f32x4;

union bfpack { ushort_t u[8]; bf16x8 v; };

__device__ __forceinline__ float sigmoidf_(float x){ return 1.0f/(1.0f + __expf(-x)); }

__device__ __forceinline__ ushort_t f2bf(float x){
    union { float f; uint32_t u; } v; v.f = x;
    uint32_t r = (v.u + 0x7FFFu + ((v.u >> 16) & 1u)) >> 16;
    return (ushort_t)r;
}
__device__ __forceinline__ float bf2f(ushort_t b){
    union { uint32_t u; float f; } v; v.u = ((uint32_t)b) << 16;
    return v.f;
}

__device__ __forceinline__ void gload16(const void* g, void* l){
    __builtin_amdgcn_global_load_lds((const __attribute__((address_space(1))) void*)g,
                                     (__attribute__((address_space(3))) void*)l, 16, 0, 0);
}

// ---------------- prep: pack big-conv weights [192][256] and wz [256][128] to bf16
__global__ __launch_bounds__(256) void k_prep(
    const float* __restrict__ wv1, const float* __restrict__ wq1, const float* __restrict__ wq2,
    const float* __restrict__ wz,
    ushort_t* __restrict__ Wbig, ushort_t* __restrict__ Wzb)
{
    int t = blockIdx.x*256 + threadIdx.x;          // 0..81919
    if (t < 49152){
        int o = t >> 8, c = t & 255;
        const float* w = (o < 64) ? (wv1 + (size_t)o*CH)
                       : (o < 128) ? (wq1 + (size_t)(o-64)*CH)
                                   : (wq2 + (size_t)(o-128)*CH);
        Wbig[t] = f2bf(w[c]);
    } else {
        int i = t - 49152;                          // 0..32767
        Wzb[i] = f2bf(wz[i]);
    }
}

// ---------------- K1: fused transpose + bf16 MFMA GEMM over ALL 8 images
// C[192][pix] = Wbig[192][256] * X[256][pix]; BM=192, BN=128, BK=64, 8 waves (4M x 2N)
__global__ __launch_bounds__(512) void k_gemm_big(
    const float* __restrict__ x,       // [8][256][16384] f32
    const ushort_t* __restrict__ Wb,   // [192][256] bf16
    const float* __restrict__ s1, const float* __restrict__ b1,
    const float* __restrict__ s2, const float* __restrict__ b2,
    ushort_t* __restrict__ value, ushort_t* __restrict__ query, ushort_t* __restrict__ query2)
{
    __shared__ ushort_t At[192*64];    // 24KB (swizzled)
    __shared__ ushort_t Bt[128*64];    // 16KB (swizzled)
    int blk = blockIdx.x;              // 1024 = 8 img * 128 px-tiles
    int n = blk >> 7;
    int pix0 = (blk & 127) << 7;       // 128-pixel tile
    int t = threadIdx.x;
    int lane = t & 63;
    int w8 = t >> 6;                   // wave 0..7
    int wm = w8 >> 1, wn = w8 & 1;     // 4(M) x 2(N); wave tile 48 x 64

    f32x4 acc[3][4];
    #pragma unroll
    for (int m=0;m<3;m++)
        #pragma unroll
        for (int nn=0;nn<4;nn++) acc[m][nn] = (f32x4){0.f,0.f,0.f,0.f};

    const float* xb = x + (size_t)n*CH*HW + pix0;
    for (int kt=0; kt<4; ++kt){
        int c0 = kt*64;
        // stage A (async gload_lds): 1536 16B-chunks, 3/thread; pre-swizzled source
        #pragma unroll
        for (int i=0;i<3;i++){
            int g = i*512 + t;
            int s = g ^ ((g>>3)&7);
            gload16(Wb + (size_t)(s>>3)*CH + c0 + (s&7)*8, (char*)At + g*16);
        }
        // stage B via registers (fused transpose+convert):
        // thread: 8 channels (c_local = 8*w8+j) x 2 px (lane, lane+64); coalesced 256B rows
        const float* xc = xb + (size_t)(c0 + 8*w8)*HW;
        float va[8], vb[8];
        #pragma unroll
        for (int j=0;j<8;j++){
            va[j] = xc[(size_t)j*HW + lane];
            vb[j] = xc[(size_t)j*HW + 64 + lane];
        }
        uint32_t pa[4], pb[4];
        #pragma unroll
        for (int j=0;j<4;j++){
            pa[j] = (uint32_t)f2bf(va[2*j]) | ((uint32_t)f2bf(va[2*j+1]) << 16);
            pb[j] = (uint32_t)f2bf(vb[2*j]) | ((uint32_t)f2bf(vb[2*j+1]) << 16);
        }
        int c2 = (8*w8)*2;             // byte column in 128B row
        int offA = (lane*128 + c2) ^ ((lane&7)<<4);
        int offB = ((lane+64)*128 + c2) ^ ((lane&7)<<4);   // (lane+64)&7 == lane&7
        *(uint4*)((char*)Bt + offA) = make_uint4(pa[0],pa[1],pa[2],pa[3]);
        *(uint4*)((char*)Bt + offB) = make_uint4(pb[0],pb[1],pb[2],pb[3]);
        __syncthreads();
        #pragma unroll
        for (int ks=0; ks<2; ++ks){
            bf16x8 a[3], b[4];
            #pragma unroll
            for (int m=0;m<3;m++){
                int row = wm*48 + m*16 + (lane&15);
                int off = (row*128 + ks*64 + (lane>>4)*16) ^ ((row&7)<<4);
                a[m] = *(const bf16x8*)((const char*)At + off);
            }
            #pragma unroll
            for (int nn=0;nn<4;nn++){
                int row = wn*64 + nn*16 + (lane&15);
                int off = (row*128 + ks*64 + (lane>>4)*16) ^ ((row&7)<<4);
                b[nn] = *(const bf16x8*)((const char*)Bt + off);
            }
            #pragma unroll
            for (int m=0;m<3;m++)
                #pragma unroll
                for (int nn=0;nn<4;nn++)
                    acc[m][nn] = __builtin_amdgcn_mfma_f32_16x16x32_bf16(a[m], b[nn], acc[m][nn], 0, 0, 0);
        }
        __syncthreads();
    }
    // epilogue: C/D layout col=lane&15 (pix), row=(lane>>4)*4+reg (o)
    float inv = rsqrtf(1.0f + EPSB);
    #pragma unroll
    for (int m=0;m<3;m++){
        int obase = wm*48 + m*16 + ((lane>>4)<<2);
        #pragma unroll
        for (int r=0;r<4;r++){
            int o = obase + r;
            int grp = o >> 6, oc = o & 63;
            float sc = 1.f, bb = 0.f;
            ushort_t* dst;
            if (grp == 0) dst = value;
            else if (grp == 1){ sc = s1[oc]*inv; bb = b1[oc]; dst = query; }
            else              { sc = s2[oc]*inv; bb = b2[oc]; dst = query2; }
            #pragma unroll
            for (int nn=0;nn<4;nn++){
                int pix = pix0 + wn*64 + nn*16 + (lane&15);
                float v = acc[m][nn][r];
                if (grp) v = fmaxf(fmaf(v, sc, bb), 0.f);
                dst[((size_t)(n*NECK + oc))*HW + pix] = f2bf(v);
            }
        }
    }
}

// ---------------- K2: small conv (fp32): other[8,512,1024] -> k1s/k2s fp32
__global__ __launch_bounds__(256) void k_conv_small(
    const float* __restrict__ x,
    const float* __restrict__ wk1, const float* __restrict__ wk2,
    const float* __restrict__ sk1, const float* __restrict__ bk1,
    const float* __restrict__ sk2, const float* __restrict__ bk2,
    float* __restrict__ k1small, float* __restrict__ k2small)
{
    __shared__ float xt[64][64];
    __shared__ float wt[64][132];
    int T = blockIdx.x;
    int n = T >> 4;
    int pix0 = (T & 15) * 64;
    int t = threadIdx.x;
    int to = t >> 4;
    int tp = t & 15;
    float acc[8][4];
    #pragma unroll
    for (int i=0;i<8;i++){ acc[i][0]=0.f;acc[i][1]=0.f;acc[i][2]=0.f;acc[i][3]=0.f; }

    const float* xb = x + (size_t)n*CL*HWS + pix0;
    for (int cc=0; cc<8; ++cc){
        #pragma unroll
        for (int i=0;i<16;i++){
            int e = i*256 + t;
            int c = e >> 6, p = e & 63;
            xt[c][p] = xb[(size_t)(cc*64 + c)*HWS + p];
        }
        #pragma unroll
        for (int i=0;i<32;i++){
            int e = i*256 + t;
            int o = e >> 6, c = e & 63;
            const float* wsrc = (o < 64) ? (wk1 + (size_t)o*CL) : (wk2 + (size_t)(o-64)*CL);
            wt[c][o] = wsrc[cc*64 + c];
        }
        __syncthreads();
        #pragma unroll 4
        for (int c=0;c<64;c++){
            float4 xv = *(const float4*)&xt[c][tp*4];
            const float4* wr = (const float4*)&wt[c][to*8];
            float4 wa = wr[0], wb = wr[1];
            float wv[8] = {wa.x,wa.y,wa.z,wa.w, wb.x,wb.y,wb.z,wb.w};
            #pragma unroll
            for (int i=0;i<8;i++){
                acc[i][0] = fmaf(wv[i], xv.x, acc[i][0]);
                acc[i][1] = fmaf(wv[i], xv.y, acc[i][1]);
                acc[i][2] = fmaf(wv[i], xv.z, acc[i][2]);
                acc[i][3] = fmaf(wv[i], xv.w, acc[i][3]);
            }
        }
        __syncthreads();
    }
    float inv = rsqrtf(1.0f + EPSB);
    #pragma unroll
    for (int i=0;i<8;i++){
        int o = to*8 + i;
        int g = o >> 6, oc = o & 63;
        float sc = (g ? sk2[oc] : sk1[oc]) * inv;
        float bb =  g ? bk2[oc] : bk1[oc];
        float4 r;
        r.x = fmaxf(fmaf(acc[i][0],sc,bb), 0.f);
        r.y = fmaxf(fmaf(acc[i][1],sc,bb), 0.f);
        r.z = fmaxf(fmaf(acc[i][2],sc,bb), 0.f);
        r.w = fmaxf(fmaf(acc[i][3],sc,bb), 0.f);
        float* dst = g ? k2small : k1small;
        *(float4*)&dst[(size_t)(n*NECK + oc)*HWS + pix0 + tp*4] = r;
    }
}

// ---------------- K3: MFMA gates. blocks 0..255 scale-1 (P=16, L=1024, ch 0..31),
//                  256..511 scale-2 (P=64, L=256, ch 32..63). 256 thr (4 waves).
__global__ __launch_bounds__(256) void k_gates(
    const ushort_t* __restrict__ query, const float* __restrict__ k1small,
    float* __restrict__ gate1, float* __restrict__ gate2)
{
    __shared__ __align__(16) char smem[69632];   // ksm 4K | qt 32K | kt 32K  (pw/simM alias front)
    int bid = blockIdx.x;
    int t = threadIdx.x;
    int lane = t & 63, wv = t >> 6;
    int r16 = lane & 15, g = lane >> 4;
    float* ksm = (float*)smem;
    ushort_t* qt = (ushort_t*)(smem + 4096);
    ushort_t* kt = (ushort_t*)(smem + 4096 + 32768);

    if (bid < 256){
        // ---- scale 1: sim[16][16] over L=1024
        int n = bid >> 5, c = bid & 31;
        const float* ks = k1small + (size_t)(n*NECK + c)*HWS;
        #pragma unroll
        for (int i=0;i<4;i++) ksm[i*256+t] = ks[i*256+t];
        __syncthreads();
        const ushort_t* qb = query + (size_t)(n*NECK + c)*HW;
        #pragma unroll
        for (int i=0;i<8;i++){
            int task = i*256 + t;            // 2048 = 16p x 128 c8
            int p = task >> 7, c8 = task & 127;
            int ly = c8 >> 2, lx8 = (c8 & 3)*8;
            int h = (p>>2)*32 + ly, w = (p&3)*32 + lx8;
            bf16x8 qv = *(const bf16x8*)(qb + h*W_ + w);
            int off = (p*2048 + c8*16) ^ ((p&7)<<4);
            *(bf16x8*)((char*)qt + off) = qv;
            float yf = h*SC31; int y0=(int)yf; int y1=min(y0+1,31); float fy=yf-(float)y0;
            bfpack pk;
            #pragma unroll
            for (int j=0;j<8;j++){
                int ww = w + j;
                float xf = ww*SC31; int x0=(int)xf; int x1=min(x0+1,31); float fx=xf-(float)x0;
                float a=ksm[y0*32+x0], b=ksm[y0*32+x1], cc=ksm[y1*32+x0], d=ksm[y1*32+x1];
                float r0=a+(b-a)*fx, r1=cc+(d-cc)*fx;
                pk.u[j] = f2bf(r0 + (r1-r0)*fy);
            }
            *(bf16x8*)((char*)kt + off) = pk.v;
        }
        __syncthreads();
        // wave wv accumulates K-chunk [wv*256, +256)
        f32x4 acc = (f32x4){0.f,0.f,0.f,0.f};
        #pragma unroll
        for (int k8=0; k8<8; ++k8){
            int l0 = wv*256 + k8*32 + g*8;
            int off = (r16*2048 + l0*2) ^ ((r16&7)<<4);
            bf16x8 av = *(const bf16x8*)((char*)qt + off);
            bf16x8 bv = *(const bf16x8*)((char*)kt + off);
            acc = __builtin_amdgcn_mfma_f32_16x16x32_bf16(av, bv, acc, 0, 0, 0);
        }
        __syncthreads();                      // qt/kt reads done; aliasing below is safe
        float* pw = (float*)smem;             // [4][256]
        #pragma unroll
        for (int r=0;r<4;r++)
            pw[wv*256 + (g*4+r)*16 + r16] = acc[r];
        __syncthreads();
        float* simM = (float*)(smem + 4096);  // [256]
        float s = pw[t] + pw[256+t] + pw[512+t] + pw[768+t];
        simM[t] = sigmoidf_(s);
        __syncthreads();
        if (t < 16){
            float rs=0.f, cs=0.f;
            #pragma unroll
            for (int q=0;q<16;q++) rs += simM[t*16+q];
            #pragma unroll
            for (int p=0;p<16;p++) cs += simM[p*16+t];
            gate1[(size_t)(n*32 + c)*16 + t] = (rs + cs) * (1.0f/16.0f);
        }
    } else {
        // ---- scale 2: sim[64][64] over L=256
        int b2 = bid - 256;
        int n = b2 >> 5, cl = b2 & 31, c = 32 + cl;
        const float* ks = k1small + (size_t)(n*NECK + c)*HWS;
        #pragma unroll
        for (int i=0;i<4;i++) ksm[i*256+t] = ks[i*256+t];
        __syncthreads();
        const ushort_t* qb = query + (size_t)(n*NECK + c)*HW;
        #pragma unroll
        for (int i=0;i<8;i++){
            int task = i*256 + t;            // 2048 = 64p x 32 c8
            int p = task >> 5, c8 = task & 31;
            int ly = c8 >> 1, lx8 = (c8 & 1)*8;
            int h = (p>>3)*16 + ly, w = (p&7)*16 + lx8;
            bf16x8 qv = *(const bf16x8*)(qb + h*W_ + w);
            int off = (p*512 + c8*16) ^ ((p&7)<<4);
            *(bf16x8*)((char*)qt + off) = qv;
            float yf = h*SC31; int y0=(int)yf; int y1=min(y0+1,31); float fy=yf-(float)y0;
            bfpack pk;
            #pragma unroll
            for (int j=0;j<8;j++){
                int ww = w + j;
                float xf = ww*SC31; int x0=(int)xf; int x1=min(x0+1,31); float fx=xf-(float)x0;
                float a=ksm[y0*32+x0], b=ksm[y0*32+x1], cc=ksm[y1*32+x0], d=ksm[y1*32+x1];
                float r0=a+(b-a)*fx, r1=cc+(d-cc)*fx;
                pk.u[j] = f2bf(r0 + (r1-r0)*fy);
            }
            *(bf16x8*)((char*)kt + off) = pk.v;
        }
        __syncthreads();
        // wave wv owns p-rows [wv*16, +16), all 64 q, full K=256
        f32x4 acc2[4];
        #pragma unroll
        for (int qc=0;qc<4;qc++) acc2[qc] = (f32x4){0.f,0.f,0.f,0.f};
        #pragma unroll
        for (int k8=0; k8<8; ++k8){
            int l0 = k8*32 + g*8;
            int offA = ((wv*16 + r16)*512 + l0*2) ^ ((r16&7)<<4);
            bf16x8 av = *(const bf16x8*)((char*)qt + offA);
            #pragma unroll
            for (int qc=0;qc<4;qc++){
                int offB = ((qc*16 + r16)*512 + l0*2) ^ ((r16&7)<<4);
                bf16x8 bv = *(const bf16x8*)((char*)kt + offB);
                acc2[qc] = __builtin_amdgcn_mfma_f32_16x16x32_bf16(av, bv, acc2[qc], 0, 0, 0);
            }
        }
        __syncthreads();                      // qt/kt reads done; simM aliases front
        float* simM = (float*)smem;           // [64][65]
        #pragma unroll
        for (int qc=0;qc<4;qc++)
            #pragma unroll
            for (int r=0;r<4;r++){
                int p = wv*16 + g*4 + r, q = qc*16 + r16;
                simM[p*65 + q] = sigmoidf_(acc2[qc][r]);
            }
        __syncthreads();
        if (t < 64){
            float rs=0.f, cs=0.f;
            for (int q=0;q<64;q++) rs += simM[t*65 + q];
            for (int p=0;p<64;p++) cs += simM[p*65 + t];
            gate2[(size_t)(n*32 + cl)*64 + t] = (rs + cs) * (1.0f/64.0f);
        }
    }
}

// ---------------- K4: context build + final conv via bf16 MFMA (A direct from global)
// block = 1 image-row (128 px), 512 threads (8 waves: 4M x 2N), BM=256, BN=128, K=128
__global__ __launch_bounds__(512, 4) void k_final_mfma(
    const ushort_t* __restrict__ value, const ushort_t* __restrict__ query2,
    const float* __restrict__ k2small,
    const float* __restrict__ gate1, const float* __restrict__ gate2,
    const ushort_t* __restrict__ Wzb,   // [256][128] bf16
    const float* __restrict__ alpha_p, const float* __restrict__ gamma_p,
    float* __restrict__ out)
{
    __shared__ __align__(16) char smem[59392];  // Ct 32K | g1s 2K | g2s 8K | k2r 16K
    ushort_t* Ct = (ushort_t*)smem;
    float* g1s = (float*)(smem + 32768);
    float* g2s = (float*)(smem + 34816);
    float* k2r = (float*)(smem + 43008);        // [2][2048]
    int blk = blockIdx.x;
    int n = blk >> 7, h = blk & 127;
    int pix0 = h << 7;
    int t = threadIdx.x;
    int lane = t & 63;
    int wid = t >> 6;
    int wm = wid >> 1, wn = wid & 1;

    float alpha = alpha_p[0], gamma = gamma_p[0];
    g1s[t & 511] = gate1[(size_t)n*512 + (t & 511)];
    #pragma unroll
    for (int i=0;i<4;i++) g2s[i*512 + t] = gate2[(size_t)n*2048 + i*512 + t];

    float yf = h * SC31;
    int y0 = (int)yf, y1 = min(y0+1, 31);
    float fy = yf - (float)y0;
    #pragma unroll
    for (int i=0;i<8;i++){
        int e = i*512 + t;              // 4096
        int buf = e >> 11, c = (e >> 5) & 63, xx = e & 31;
        k2r[buf*2048 + c*32 + xx] = k2small[((size_t)n*NECK + c)*HWS + (buf ? y1 : y0)*32 + xx];
    }
    __syncthreads();

    // ctx build: thread -> (px, 32-channel group); write bf16x8 chunks swizzled
    int px = t & 127, chg = t >> 7;
    int w = px;
    float xf = w * SC31;
    int x0 = (int)xf, x1 = min(x0+1, 31);
    float fx = xf - (float)x0;
    int patch1 = (h>>5)*4 + (w>>5);
    int patch2 = (h>>4)*8 + (w>>4);
    int ch0 = chg*32;
    const size_t vbase = (size_t)n*NECK*HW + pix0 + px;
    #pragma unroll
    for (int j=0;j<4;j++){
        bfpack pk;
        #pragma unroll
        for (int i=0;i<8;i++){
            int ch = ch0 + j*8 + i;
            float v;
            if (chg < 2){
                float g = (ch < 32) ? g1s[ch*16 + patch1] : g2s[(ch-32)*64 + patch2];
                v = alpha * g * bf2f(value[vbase + (size_t)ch*HW]);
            } else {
                int c = ch - 64;
                float vv = bf2f(value[vbase + (size_t)c*HW]);
                float q2 = bf2f(query2[vbase + (size_t)c*HW]);
                float r0 = k2r[c*32+x0];      r0 += (k2r[c*32+x1] - r0)*fx;
                float r1 = k2r[2048+c*32+x0]; r1 += (k2r[2048+c*32+x1] - r1)*fx;
                float kv = r0 + (r1 - r0)*fy;
                v = gamma * vv * sigmoidf_(q2*kv);
            }
            pk.u[i] = f2bf(v);
        }
        int off = (px*256 + ch0*2 + j*16) ^ ((px&7)<<4);
        *(bf16x8*)((char*)Ct + off) = pk.v;
    }
    __syncthreads();

    // MFMA: wave tile 64(o) x 64(px), K=128 in 4 steps; A-frags direct from global (L2)
    f32x4 acc[4][4];
    #pragma unroll
    for (int m=0;m<4;m++)
        #pragma unroll
        for (int nn=0;nn<4;nn++) acc[m][nn] = (f32x4){0.f,0.f,0.f,0.f};
    #pragma unroll
    for (int ks=0; ks<4; ++ks){
        bf16x8 a[4], b[4];
        #pragma unroll
        for (int m=0;m<4;m++){
            int row = wm*64 + m*16 + (lane&15);
            a[m] = *(const bf16x8*)(Wzb + row*128 + ks*32 + (lane>>4)*8);
        }
        #pragma unroll
        for (int nn=0;nn<4;nn++){
            int row = wn*64 + nn*16 + (lane&15);
            int off = (row*256 + ks*64 + (lane>>4)*16) ^ ((row&7)<<4);
            b[nn] = *(const bf16x8*)((const char*)Ct + off);
        }
        #pragma unroll
        for (int m=0;m<4;m++)
            #pragma unroll
            for (int nn=0;nn<4;nn++)
                acc[m][nn] = __builtin_amdgcn_mfma_f32_16x16x32_bf16(a[m], b[nn], acc[m][nn], 0, 0, 0);
    }

    // epilogue: o = row, px = col
    #pragma unroll
    for (int m=0;m<4;m++){
        int obase = wm*64 + m*16 + ((lane>>4)<<2);
        #pragma unroll
        for (int r=0;r<4;r++){
            int o = obase + r;
            float* dst = out + ((size_t)(n*CH + o))*HW + pix0 + wn*64 + (lane&15);
            #pragma unroll
            for (int nn=0;nn<4;nn++)
                dst[nn*16] = acc[m][nn][r];
        }
    }
}

extern "C" void kernel_launch(void* const* d_in, const int* in_sizes, int n_in,
                              void* d_out, int out_size, void* d_ws, size_t ws_size,
                              hipStream_t stream) {
    const float* x0  = (const float*)d_in[0];
    const float* xo  = (const float*)d_in[1];
    const float* wq1 = (const float*)d_in[2];
    const float* s1  = (const float*)d_in[3];
    const float* b1  = (const float*)d_in[4];
    const float* wk1 = (const float*)d_in[5];
    const float* sk1 = (const float*)d_in[6];
    const float* bk1 = (const float*)d_in[7];
    const float* wv1 = (const float*)d_in[8];
    const float* wq2 = (const float*)d_in[9];
    const float* s2  = (const float*)d_in[10];
    const float* b2  = (const float*)d_in[11];
    const float* wk2 = (const float*)d_in[12];
    const float* sk2 = (const float*)d_in[13];
    const float* bk2 = (const float*)d_in[14];
    const float* wz  = (const float*)d_in[15];
    const float* alp = (const float*)d_in[16];
    const float* gam = (const float*)d_in[17];

    // workspace layout (all 16B-aligned): ~55 MB total
    ushort_t* value  = (ushort_t*)d_ws;          // 8*64*16384
    ushort_t* query  = value  + 8388608;
    ushort_t* query2 = query  + 8388608;
    float*    k1s    = (float*)(query2 + 8388608);   // 8*64*1024
    float*    k2s    = k1s + 524288;
    float*    g1     = k2s + 524288;             // 8*32*16
    float*    g2     = g1 + 4096;                // 8*32*64
    ushort_t* Wbig   = (ushort_t*)(g2 + 16384);  // 192*256
    ushort_t* Wzb    = Wbig + 49152;             // 256*128

    k_prep<<<dim3(320), dim3(256), 0, stream>>>(wv1, wq1, wq2, wz, Wbig, Wzb);
    k_gemm_big<<<dim3(1024), dim3(512), 0, stream>>>(
        x0, Wbig, s1, b1, s2, b2, value, query, query2);
    k_conv_small<<<dim3(128), dim3(256), 0, stream>>>(xo, wk1, wk2, sk1, bk1, sk2, bk2,
                                                      k1s, k2s);
    k_gates<<<dim3(512), dim3(256), 0, stream>>>(query, k1s, g1, g2);
    k_final_mfma<<<dim3(1024), dim3(512), 0, stream>>>(value, query2, k2s, g1, g2, Wzb,
                                                       alp, gam, (float*)d_out);
}

// Round 6
// 153.271 us; speedup vs baseline: 4.1814x; 1.0697x over previous
//
#include <hip/hip_runtime.h>
#include <math.h>
#include <stdint.h>

#define N_    8
#define CH    256
#define CL    512
#define NECK  64
#define H_    128
#define W_    128
#define HW    16384
#define HWS   1024
#define EPSB  1e-5f
#define SC31  (31.0f/127.0f)

typedef unsigned short ushort_t;
typedef __attribute__((ext_vector_type(8))) short bf16x8;
typedef __attribute__((ext_vector_type(4))) float f32x4;

union bfpack { ushort_t u[8]; bf16x8 v; };

__device__ __forceinline__ float sigmoidf_(float x){ return 1.0f/(1.0f + __expf(-x)); }

__device__ __forceinline__ ushort_t f2bf(float x){
    union { float f; uint32_t u; } v; v.f = x;
    uint32_t r = (v.u + 0x7FFFu + ((v.u >> 16) & 1u)) >> 16;
    return (ushort_t)r;
}
__device__ __forceinline__ float bf2f(ushort_t b){
    union { uint32_t u; float f; } v; v.u = ((uint32_t)b) << 16;
    return v.f;
}

__device__ __forceinline__ void gload16(const void* g, void* l){
    __builtin_amdgcn_global_load_lds((const __attribute__((address_space(1))) void*)g,
                                     (__attribute__((address_space(3))) void*)l, 16, 0, 0);
}

// ---------------- K0: small conv (fp32) + weight prep in one grid
// blocks 0..127: conv_small ; blocks 128..447: pack Wbig/Wzb bf16
__global__ __launch_bounds__(256) void k_conv_small_prep(
    const float* __restrict__ x,
    const float* __restrict__ wk1, const float* __restrict__ wk2,
    const float* __restrict__ sk1, const float* __restrict__ bk1,
    const float* __restrict__ sk2, const float* __restrict__ bk2,
    const float* __restrict__ wv1, const float* __restrict__ wq1, const float* __restrict__ wq2,
    const float* __restrict__ wz,
    float* __restrict__ k1small, float* __restrict__ k2small,
    ushort_t* __restrict__ Wbig, ushort_t* __restrict__ Wzb)
{
    __shared__ float xt[64][64];
    __shared__ float wt[64][132];
    if (blockIdx.x >= 128){
        int t = (blockIdx.x - 128)*256 + threadIdx.x;   // 0..81919
        if (t < 49152){
            int o = t >> 8, c = t & 255;
            const float* w = (o < 64) ? (wv1 + (size_t)o*CH)
                           : (o < 128) ? (wq1 + (size_t)(o-64)*CH)
                                       : (wq2 + (size_t)(o-128)*CH);
            Wbig[t] = f2bf(w[c]);
        } else {
            int i = t - 49152;
            Wzb[i] = f2bf(wz[i]);
        }
        return;
    }
    int T = blockIdx.x;
    int n = T >> 4;
    int pix0 = (T & 15) * 64;
    int t = threadIdx.x;
    int to = t >> 4;
    int tp = t & 15;
    float acc[8][4];
    #pragma unroll
    for (int i=0;i<8;i++){ acc[i][0]=0.f;acc[i][1]=0.f;acc[i][2]=0.f;acc[i][3]=0.f; }

    const float* xb = x + (size_t)n*CL*HWS + pix0;
    for (int cc=0; cc<8; ++cc){
        #pragma unroll
        for (int i=0;i<16;i++){
            int e = i*256 + t;
            int c = e >> 6, p = e & 63;
            xt[c][p] = xb[(size_t)(cc*64 + c)*HWS + p];
        }
        #pragma unroll
        for (int i=0;i<32;i++){
            int e = i*256 + t;
            int o = e >> 6, c = e & 63;
            const float* wsrc = (o < 64) ? (wk1 + (size_t)o*CL) : (wk2 + (size_t)(o-64)*CL);
            wt[c][o] = wsrc[cc*64 + c];
        }
        __syncthreads();
        #pragma unroll 4
        for (int c=0;c<64;c++){
            float4 xv = *(const float4*)&xt[c][tp*4];
            const float4* wr = (const float4*)&wt[c][to*8];
            float4 wa = wr[0], wb = wr[1];
            float wv[8] = {wa.x,wa.y,wa.z,wa.w, wb.x,wb.y,wb.z,wb.w};
            #pragma unroll
            for (int i=0;i<8;i++){
                acc[i][0] = fmaf(wv[i], xv.x, acc[i][0]);
                acc[i][1] = fmaf(wv[i], xv.y, acc[i][1]);
                acc[i][2] = fmaf(wv[i], xv.z, acc[i][2]);
                acc[i][3] = fmaf(wv[i], xv.w, acc[i][3]);
            }
        }
        __syncthreads();
    }
    float inv = rsqrtf(1.0f + EPSB);
    #pragma unroll
    for (int i=0;i<8;i++){
        int o = to*8 + i;
        int g = o >> 6, oc = o & 63;
        float sc = (g ? sk2[oc] : sk1[oc]) * inv;
        float bb =  g ? bk2[oc] : bk1[oc];
        float4 r;
        r.x = fmaxf(fmaf(acc[i][0],sc,bb), 0.f);
        r.y = fmaxf(fmaf(acc[i][1],sc,bb), 0.f);
        r.z = fmaxf(fmaf(acc[i][2],sc,bb), 0.f);
        r.w = fmaxf(fmaf(acc[i][3],sc,bb), 0.f);
        float* dst = g ? k2small : k1small;
        *(float4*)&dst[(size_t)(n*NECK + oc)*HWS + pix0 + tp*4] = r;
    }
}

// ---------------- K1: fused transpose + bf16 MFMA GEMM over ALL 8 images
// C[192][pix] = Wbig[192][256] * X[256][pix]; BM=192, BN=128, BK=64, 8 waves (4M x 2N)
// x-loads for kt+1 prefetched into regs during MFMA(kt) to hide HBM latency.
__global__ __launch_bounds__(512) void k_gemm_big(
    const float* __restrict__ x,       // [8][256][16384] f32
    const ushort_t* __restrict__ Wb,   // [192][256] bf16
    const float* __restrict__ s1, const float* __restrict__ b1,
    const float* __restrict__ s2, const float* __restrict__ b2,
    ushort_t* __restrict__ value, ushort_t* __restrict__ query, ushort_t* __restrict__ query2)
{
    __shared__ ushort_t At[192*64];    // 24KB (swizzled)
    __shared__ ushort_t Bt[128*64];    // 16KB (swizzled)
    int blk = blockIdx.x;              // 1024 = 8 img * 128 px-tiles
    int n = blk >> 7;
    int pix0 = (blk & 127) << 7;       // 128-pixel tile
    int t = threadIdx.x;
    int lane = t & 63;
    int w8 = t >> 6;                   // wave 0..7
    int wm = w8 >> 1, wn = w8 & 1;     // 4(M) x 2(N); wave tile 48 x 64

    f32x4 acc[3][4];
    #pragma unroll
    for (int m=0;m<3;m++)
        #pragma unroll
        for (int nn=0;nn<4;nn++) acc[m][nn] = (f32x4){0.f,0.f,0.f,0.f};

    const float* xb = x + (size_t)n*CH*HW + pix0;
    // prologue: kt=0 x-rows into regs
    float va[8], vb[8];
    {
        const float* xc = xb + (size_t)(8*w8)*HW;
        #pragma unroll
        for (int j=0;j<8;j++){
            va[j] = xc[(size_t)j*HW + lane];
            vb[j] = xc[(size_t)j*HW + 64 + lane];
        }
    }
    for (int kt=0; kt<4; ++kt){
        int c0 = kt*64;
        // stage A (async gload_lds): 1536 16B-chunks, 3/thread; pre-swizzled source
        #pragma unroll
        for (int i=0;i<3;i++){
            int g = i*512 + t;
            int s = g ^ ((g>>3)&7);
            gload16(Wb + (size_t)(s>>3)*CH + c0 + (s&7)*8, (char*)At + g*16);
        }
        // stage B from regs (fused transpose+convert)
        uint32_t pa[4], pb[4];
        #pragma unroll
        for (int j=0;j<4;j++){
            pa[j] = (uint32_t)f2bf(va[2*j]) | ((uint32_t)f2bf(va[2*j+1]) << 16);
            pb[j] = (uint32_t)f2bf(vb[2*j]) | ((uint32_t)f2bf(vb[2*j+1]) << 16);
        }
        int c2 = (8*w8)*2;             // byte column in 128B row
        int offA = (lane*128 + c2) ^ ((lane&7)<<4);
        int offB = ((lane+64)*128 + c2) ^ ((lane&7)<<4);   // (lane+64)&7 == lane&7
        *(uint4*)((char*)Bt + offA) = make_uint4(pa[0],pa[1],pa[2],pa[3]);
        *(uint4*)((char*)Bt + offB) = make_uint4(pb[0],pb[1],pb[2],pb[3]);
        __syncthreads();
        // prefetch next kt's x-rows; they fly during the MFMA phase
        if (kt < 3){
            const float* xc = xb + (size_t)((kt+1)*64 + 8*w8)*HW;
            #pragma unroll
            for (int j=0;j<8;j++){
                va[j] = xc[(size_t)j*HW + lane];
                vb[j] = xc[(size_t)j*HW + 64 + lane];
            }
        }
        #pragma unroll
        for (int ks=0; ks<2; ++ks){
            bf16x8 a[3], b[4];
            #pragma unroll
            for (int m=0;m<3;m++){
                int row = wm*48 + m*16 + (lane&15);
                int off = (row*128 + ks*64 + (lane>>4)*16) ^ ((row&7)<<4);
                a[m] = *(const bf16x8*)((const char*)At + off);
            }
            #pragma unroll
            for (int nn=0;nn<4;nn++){
                int row = wn*64 + nn*16 + (lane&15);
                int off = (row*128 + ks*64 + (lane>>4)*16) ^ ((row&7)<<4);
                b[nn] = *(const bf16x8*)((const char*)Bt + off);
            }
            #pragma unroll
            for (int m=0;m<3;m++)
                #pragma unroll
                for (int nn=0;nn<4;nn++)
                    acc[m][nn] = __builtin_amdgcn_mfma_f32_16x16x32_bf16(a[m], b[nn], acc[m][nn], 0, 0, 0);
        }
        __syncthreads();
    }
    // epilogue: C/D layout col=lane&15 (pix), row=(lane>>4)*4+reg (o)
    float inv = rsqrtf(1.0f + EPSB);
    #pragma unroll
    for (int m=0;m<3;m++){
        int obase = wm*48 + m*16 + ((lane>>4)<<2);
        #pragma unroll
        for (int r=0;r<4;r++){
            int o = obase + r;
            int grp = o >> 6, oc = o & 63;
            float sc = 1.f, bb = 0.f;
            ushort_t* dst;
            if (grp == 0) dst = value;
            else if (grp == 1){ sc = s1[oc]*inv; bb = b1[oc]; dst = query; }
            else              { sc = s2[oc]*inv; bb = b2[oc]; dst = query2; }
            #pragma unroll
            for (int nn=0;nn<4;nn++){
                int pix = pix0 + wn*64 + nn*16 + (lane&15);
                float v = acc[m][nn][r];
                if (grp) v = fmaxf(fmaf(v, sc, bb), 0.f);
                dst[((size_t)(n*NECK + oc))*HW + pix] = f2bf(v);
            }
        }
    }
}

// ---------------- K3: MFMA gates. blocks 0..255 scale-1 (P=16, L=1024, ch 0..31),
//                  256..511 scale-2 (P=64, L=256, ch 32..63). 256 thr (4 waves).
__global__ __launch_bounds__(256) void k_gates(
    const ushort_t* __restrict__ query, const float* __restrict__ k1small,
    float* __restrict__ gate1, float* __restrict__ gate2)
{
    __shared__ __align__(16) char smem[69632];   // ksm 4K | qt 32K | kt 32K  (pw/simM alias front)
    int bid = blockIdx.x;
    int t = threadIdx.x;
    int lane = t & 63, wv = t >> 6;
    int r16 = lane & 15, g = lane >> 4;
    float* ksm = (float*)smem;
    ushort_t* qt = (ushort_t*)(smem + 4096);
    ushort_t* kt = (ushort_t*)(smem + 4096 + 32768);

    if (bid < 256){
        // ---- scale 1: sim[16][16] over L=1024
        int n = bid >> 5, c = bid & 31;
        const float* ks = k1small + (size_t)(n*NECK + c)*HWS;
        #pragma unroll
        for (int i=0;i<4;i++) ksm[i*256+t] = ks[i*256+t];
        __syncthreads();
        const ushort_t* qb = query + (size_t)(n*NECK + c)*HW;
        #pragma unroll
        for (int i=0;i<8;i++){
            int task = i*256 + t;            // 2048 = 16p x 128 c8
            int p = task >> 7, c8 = task & 127;
            int ly = c8 >> 2, lx8 = (c8 & 3)*8;
            int h = (p>>2)*32 + ly, w = (p&3)*32 + lx8;
            bf16x8 qv = *(const bf16x8*)(qb + h*W_ + w);
            int off = (p*2048 + c8*16) ^ ((p&7)<<4);
            *(bf16x8*)((char*)qt + off) = qv;
            float yf = h*SC31; int y0=(int)yf; int y1=min(y0+1,31); float fy=yf-(float)y0;
            bfpack pk;
            #pragma unroll
            for (int j=0;j<8;j++){
                int ww = w + j;
                float xf = ww*SC31; int x0=(int)xf; int x1=min(x0+1,31); float fx=xf-(float)x0;
                float a=ksm[y0*32+x0], b=ksm[y0*32+x1], cc=ksm[y1*32+x0], d=ksm[y1*32+x1];
                float r0=a+(b-a)*fx, r1=cc+(d-cc)*fx;
                pk.u[j] = f2bf(r0 + (r1-r0)*fy);
            }
            *(bf16x8*)((char*)kt + off) = pk.v;
        }
        __syncthreads();
        // wave wv accumulates K-chunk [wv*256, +256)
        f32x4 acc = (f32x4){0.f,0.f,0.f,0.f};
        #pragma unroll
        for (int k8=0; k8<8; ++k8){
            int l0 = wv*256 + k8*32 + g*8;
            int off = (r16*2048 + l0*2) ^ ((r16&7)<<4);
            bf16x8 av = *(const bf16x8*)((char*)qt + off);
            bf16x8 bv = *(const bf16x8*)((char*)kt + off);
            acc = __builtin_amdgcn_mfma_f32_16x16x32_bf16(av, bv, acc, 0, 0, 0);
        }
        __syncthreads();                      // qt/kt reads done; aliasing below is safe
        float* pw = (float*)smem;             // [4][256]
        #pragma unroll
        for (int r=0;r<4;r++)
            pw[wv*256 + (g*4+r)*16 + r16] = acc[r];
        __syncthreads();
        float* simM = (float*)(smem + 4096);  // [256]
        float s = pw[t] + pw[256+t] + pw[512+t] + pw[768+t];
        simM[t] = sigmoidf_(s);
        __syncthreads();
        if (t < 16){
            float rs=0.f, cs=0.f;
            #pragma unroll
            for (int q=0;q<16;q++) rs += simM[t*16+q];
            #pragma unroll
            for (int p=0;p<16;p++) cs += simM[p*16+t];
            gate1[(size_t)(n*32 + c)*16 + t] = (rs + cs) * (1.0f/16.0f);
        }
    } else {
        // ---- scale 2: sim[64][64] over L=256
        int b2 = bid - 256;
        int n = b2 >> 5, cl = b2 & 31, c = 32 + cl;
        const float* ks = k1small + (size_t)(n*NECK + c)*HWS;
        #pragma unroll
        for (int i=0;i<4;i++) ksm[i*256+t] = ks[i*256+t];
        __syncthreads();
        const ushort_t* qb = query + (size_t)(n*NECK + c)*HW;
        #pragma unroll
        for (int i=0;i<8;i++){
            int task = i*256 + t;            // 2048 = 64p x 32 c8
            int p = task >> 5, c8 = task & 31;
            int ly = c8 >> 1, lx8 = (c8 & 1)*8;
            int h = (p>>3)*16 + ly, w = (p&7)*16 + lx8;
            bf16x8 qv = *(const bf16x8*)(qb + h*W_ + w);
            int off = (p*512 + c8*16) ^ ((p&7)<<4);
            *(bf16x8*)((char*)qt + off) = qv;
            float yf = h*SC31; int y0=(int)yf; int y1=min(y0+1,31); float fy=yf-(float)y0;
            bfpack pk;
            #pragma unroll
            for (int j=0;j<8;j++){
                int ww = w + j;
                float xf = ww*SC31; int x0=(int)xf; int x1=min(x0+1,31); float fx=xf-(float)x0;
                float a=ksm[y0*32+x0], b=ksm[y0*32+x1], cc=ksm[y1*32+x0], d=ksm[y1*32+x1];
                float r0=a+(b-a)*fx, r1=cc+(d-cc)*fx;
                pk.u[j] = f2bf(r0 + (r1-r0)*fy);
            }
            *(bf16x8*)((char*)kt + off) = pk.v;
        }
        __syncthreads();
        // wave wv owns p-rows [wv*16, +16), all 64 q, full K=256
        f32x4 acc2[4];
        #pragma unroll
        for (int qc=0;qc<4;qc++) acc2[qc] = (f32x4){0.f,0.f,0.f,0.f};
        #pragma unroll
        for (int k8=0; k8<8; ++k8){
            int l0 = k8*32 + g*8;
            int offA = ((wv*16 + r16)*512 + l0*2) ^ ((r16&7)<<4);
            bf16x8 av = *(const bf16x8*)((char*)qt + offA);
            #pragma unroll
            for (int qc=0;qc<4;qc++){
                int offB = ((qc*16 + r16)*512 + l0*2) ^ ((r16&7)<<4);
                bf16x8 bv = *(const bf16x8*)((char*)kt + offB);
                acc2[qc] = __builtin_amdgcn_mfma_f32_16x16x32_bf16(av, bv, acc2[qc], 0, 0, 0);
            }
        }
        __syncthreads();                      // qt/kt reads done; simM aliases front
        float* simM = (float*)smem;           // [64][65]
        #pragma unroll
        for (int qc=0;qc<4;qc++)
            #pragma unroll
            for (int r=0;r<4;r++){
                int p = wv*16 + g*4 + r, q = qc*16 + r16;
                simM[p*65 + q] = sigmoidf_(acc2[qc][r]);
            }
        __syncthreads();
        if (t < 64){
            float rs=0.f, cs=0.f;
            for (int q=0;q<64;q++) rs += simM[t*65 + q];
            for (int p=0;p<64;p++) cs += simM[p*65 + t];
            gate2[(size_t)(n*32 + cl)*64 + t] = (rs + cs) * (1.0f/64.0f);
        }
    }
}

// ---------------- K4: context build + final conv via bf16 MFMA (A direct from global)
// block = 1 image-row (128 px), 512 threads (8 waves: 4M x 2N), BM=256, BN=128, K=128
// thread = (px, 16-ch quad): handles BOTH gate-half ch and dense-half ch+64 -> value read once,
// balanced waves; global loads issued before LDS staging to hide latency.
__global__ __launch_bounds__(512, 4) void k_final_mfma(
    const ushort_t* __restrict__ value, const ushort_t* __restrict__ query2,
    const float* __restrict__ k2small,
    const float* __restrict__ gate1, const float* __restrict__ gate2,
    const ushort_t* __restrict__ Wzb,   // [256][128] bf16
    const float* __restrict__ alpha_p, const float* __restrict__ gamma_p,
    float* __restrict__ out)
{
    __shared__ __align__(16) char smem[59392];  // Ct 32K | g1s 2K | g2s 8K | k2r 16K
    ushort_t* Ct = (ushort_t*)smem;
    float* g1s = (float*)(smem + 32768);
    float* g2s = (float*)(smem + 34816);
    float* k2r = (float*)(smem + 43008);        // [2][2048]
    int blk = blockIdx.x;
    int n = blk >> 7, h = blk & 127;
    int pix0 = h << 7;
    int t = threadIdx.x;
    int lane = t & 63;
    int wid = t >> 6;
    int wm = wid >> 1, wn = wid & 1;

    int px = t & 127, qd = t >> 7;              // 16-channel quad
    // EARLY: issue all value/query2 loads; they fly under the LDS staging below
    const size_t vbase = (size_t)n*NECK*HW + pix0 + px;
    ushort_t vreg[16], qreg[16];
    #pragma unroll
    for (int i=0;i<16;i++){
        int c = qd*16 + i;
        vreg[i] = value [vbase + (size_t)c*HW];
        qreg[i] = query2[vbase + (size_t)c*HW];
    }

    float alpha = alpha_p[0], gamma = gamma_p[0];
    g1s[t & 511] = gate1[(size_t)n*512 + (t & 511)];
    #pragma unroll
    for (int i=0;i<4;i++) g2s[i*512 + t] = gate2[(size_t)n*2048 + i*512 + t];

    float yf = h * SC31;
    int y0 = (int)yf, y1 = min(y0+1, 31);
    float fy = yf - (float)y0;
    #pragma unroll
    for (int i=0;i<8;i++){
        int e = i*512 + t;              // 4096
        int buf = e >> 11, c = (e >> 5) & 63, xx = e & 31;
        k2r[buf*2048 + c*32 + xx] = k2small[((size_t)n*NECK + c)*HWS + (buf ? y1 : y0)*32 + xx];
    }
    __syncthreads();

    // ctx build
    float xf = px * SC31;
    int x0 = (int)xf, x1 = min(x0+1, 31);
    float fx = xf - (float)x0;
    int patch1 = (h>>5)*4 + (px>>5);
    int patch2 = (h>>4)*8 + (px>>4);
    // gate half: ch = qd*16 + j*8 + i
    #pragma unroll
    for (int j=0;j<2;j++){
        bfpack pk;
        #pragma unroll
        for (int i=0;i<8;i++){
            int ch = qd*16 + j*8 + i;
            float g = (ch < 32) ? g1s[ch*16 + patch1] : g2s[(ch-32)*64 + patch2];
            pk.u[i] = f2bf(alpha * g * bf2f(vreg[j*8+i]));
        }
        int off = (px*256 + qd*32 + j*16) ^ ((px&7)<<4);
        *(bf16x8*)((char*)Ct + off) = pk.v;
    }
    // dense half: ctx[64+c] = gamma * v * sigmoid(q2 * bilin(k2))
    #pragma unroll
    for (int j=0;j<2;j++){
        bfpack pk;
        #pragma unroll
        for (int i=0;i<8;i++){
            int c = qd*16 + j*8 + i;
            float vv = bf2f(vreg[j*8+i]);
            float q2 = bf2f(qreg[j*8+i]);
            float r0 = k2r[c*32+x0];      r0 += (k2r[c*32+x1] - r0)*fx;
            float r1 = k2r[2048+c*32+x0]; r1 += (k2r[2048+c*32+x1] - r1)*fx;
            float kv = r0 + (r1 - r0)*fy;
            pk.u[i] = f2bf(gamma * vv * sigmoidf_(q2*kv));
        }
        int off = (px*256 + 128 + qd*32 + j*16) ^ ((px&7)<<4);
        *(bf16x8*)((char*)Ct + off) = pk.v;
    }
    __syncthreads();

    // MFMA: wave tile 64(o) x 64(px), K=128 in 4 steps; A-frags direct from global (L2)
    f32x4 acc[4][4];
    #pragma unroll
    for (int m=0;m<4;m++)
        #pragma unroll
        for (int nn=0;nn<4;nn++) acc[m][nn] = (f32x4){0.f,0.f,0.f,0.f};
    #pragma unroll
    for (int ks=0; ks<4; ++ks){
        bf16x8 a[4], b[4];
        #pragma unroll
        for (int m=0;m<4;m++){
            int row = wm*64 + m*16 + (lane&15);
            a[m] = *(const bf16x8*)(Wzb + row*128 + ks*32 + (lane>>4)*8);
        }
        #pragma unroll
        for (int nn=0;nn<4;nn++){
            int row = wn*64 + nn*16 + (lane&15);
            int off = (row*256 + ks*64 + (lane>>4)*16) ^ ((row&7)<<4);
            b[nn] = *(const bf16x8*)((const char*)Ct + off);
        }
        #pragma unroll
        for (int m=0;m<4;m++)
            #pragma unroll
            for (int nn=0;nn<4;nn++)
                acc[m][nn] = __builtin_amdgcn_mfma_f32_16x16x32_bf16(a[m], b[nn], acc[m][nn], 0, 0, 0);
    }

    // epilogue: o = row, px = col
    #pragma unroll
    for (int m=0;m<4;m++){
        int obase = wm*64 + m*16 + ((lane>>4)<<2);
        #pragma unroll
        for (int r=0;r<4;r++){
            int o = obase + r;
            float* dst = out + ((size_t)(n*CH + o))*HW + pix0 + wn*64 + (lane&15);
            #pragma unroll
            for (int nn=0;nn<4;nn++)
                dst[nn*16] = acc[m][nn][r];
        }
    }
}

extern "C" void kernel_launch(void* const* d_in, const int* in_sizes, int n_in,
                              void* d_out, int out_size, void* d_ws, size_t ws_size,
                              hipStream_t stream) {
    const float* x0  = (const float*)d_in[0];
    const float* xo  = (const float*)d_in[1];
    const float* wq1 = (const float*)d_in[2];
    const float* s1  = (const float*)d_in[3];
    const float* b1  = (const float*)d_in[4];
    const float* wk1 = (const float*)d_in[5];
    const float* sk1 = (const float*)d_in[6];
    const float* bk1 = (const float*)d_in[7];
    const float* wv1 = (const float*)d_in[8];
    const float* wq2 = (const float*)d_in[9];
    const float* s2  = (const float*)d_in[10];
    const float* b2  = (const float*)d_in[11];
    const float* wk2 = (const float*)d_in[12];
    const float* sk2 = (const float*)d_in[13];
    const float* bk2 = (const float*)d_in[14];
    const float* wz  = (const float*)d_in[15];
    const float* alp = (const float*)d_in[16];
    const float* gam = (const float*)d_in[17];

    // workspace layout (all 16B-aligned): ~55 MB total
    ushort_t* value  = (ushort_t*)d_ws;          // 8*64*16384
    ushort_t* query  = value  + 8388608;
    ushort_t* query2 = query  + 8388608;
    float*    k1s    = (float*)(query2 + 8388608);   // 8*64*1024
    float*    k2s    = k1s + 524288;
    float*    g1     = k2s + 524288;             // 8*32*16
    float*    g2     = g1 + 4096;                // 8*32*64
    ushort_t* Wbig   = (ushort_t*)(g2 + 16384);  // 192*256
    ushort_t* Wzb    = Wbig + 49152;             // 256*128

    k_conv_small_prep<<<dim3(448), dim3(256), 0, stream>>>(
        xo, wk1, wk2, sk1, bk1, sk2, bk2, wv1, wq1, wq2, wz, k1s, k2s, Wbig, Wzb);
    k_gemm_big<<<dim3(1024), dim3(512), 0, stream>>>(
        x0, Wbig, s1, b1, s2, b2, value, query, query2);
    k_gates<<<dim3(512), dim3(256), 0, stream>>>(query, k1s, g1, g2);
    k_final_mfma<<<dim3(1024), dim3(512), 0, stream>>>(value, query2, k2s, g1, g2, Wzb,
                                                       alp, gam, (float*)d_out);
}

// Round 7
// 127.765 us; speedup vs baseline: 5.0161x; 1.1996x over previous
//
#include <hip/hip_runtime.h>
#include <hip/hip_bf16.h>
#include <math.h>
#include <stdint.h>

#define N_    8
#define CH    256
#define CL    512
#define NECK  64
#define H_    128
#define W_    128
#define HW    16384
#define HWS   1024
#define EPSB  1e-5f
#define SC31  (31.0f/127.0f)

typedef unsigned short ushort_t;
typedef __attribute__((ext_vector_type(8))) short bf16x8;
typedef __attribute__((ext_vector_type(4))) float f32x4;

union bfpack { ushort_t u[8]; bf16x8 v; };

__device__ __forceinline__ float sigmoidf_(float x){ return 1.0f/(1.0f + __expf(-x)); }

__device__ __forceinline__ ushort_t f2bf(float x){
    union { __hip_bfloat16 h; ushort_t u; } cv;
    cv.h = __float2bfloat16(x);              // RNE, compiler fuses pairs to v_cvt_pk_bf16_f32
    return cv.u;
}
__device__ __forceinline__ uint32_t pack2(float lo, float hi){
    return (uint32_t)f2bf(lo) | ((uint32_t)f2bf(hi) << 16);
}
__device__ __forceinline__ float bf2f(ushort_t b){
    union { uint32_t u; float f; } v; v.u = ((uint32_t)b) << 16;
    return v.f;
}

// ---------------- K1: phase-1 mega-launch, 512 threads/block
// blocks 0..1023   : big GEMM  C[192][px] = W[192][256] * X[256][px]  (A reg-staged from f32)
// blocks 1024..1087: small conv as MFMA GEMM  C[128][px] = Wk[128][512] * Xo[512][px]
// blocks 1088..1103: pack wz -> Wzb bf16
__global__ __launch_bounds__(512) void k_phase1(
    const float* __restrict__ x,       // [8][256][16384]
    const float* __restrict__ xo,      // [8][512][1024]
    const float* __restrict__ wv1, const float* __restrict__ wq1, const float* __restrict__ wq2,
    const float* __restrict__ wk1, const float* __restrict__ wk2,
    const float* __restrict__ s1, const float* __restrict__ b1,
    const float* __restrict__ s2, const float* __restrict__ b2,
    const float* __restrict__ sk1, const float* __restrict__ bk1,
    const float* __restrict__ sk2, const float* __restrict__ bk2,
    const float* __restrict__ wz,
    ushort_t* __restrict__ value, ushort_t* __restrict__ query, ushort_t* __restrict__ query2,
    float* __restrict__ k1s, float* __restrict__ k2s, ushort_t* __restrict__ Wzb)
{
    __shared__ __align__(16) char smem[40960];
    int blk = blockIdx.x;
    int t = threadIdx.x;

    if (blk >= 1088){
        // ---- Wzb pack: 16 blocks x 512 thr x 4 elems
        int i = (blk - 1088)*2048 + t*4;
        float4 f = *(const float4*)(wz + i);
        *(uint2*)(Wzb + i) = make_uint2(pack2(f.x,f.y), pack2(f.z,f.w));
        return;
    }

    int lane = t & 63, w8 = t >> 6;
    int wm = w8 >> 1, wn = w8 & 1;
    int r16 = lane & 15;
    float inv = rsqrtf(1.0f + EPSB);

    if (blk >= 1024){
        // ---- small conv MFMA: BM=128(o), BN=128(px), BK=64, 8 K-steps
        ushort_t* At = (ushort_t*)smem;            // [128][64] swizzled, 16KB
        ushort_t* Bt = (ushort_t*)(smem + 16384);  // [128][64] swizzled, 16KB
        int b = blk - 1024;
        int n = b >> 3, pix0 = (b & 7) << 7;
        f32x4 acc[2][4];
        #pragma unroll
        for (int m=0;m<2;m++)
            #pragma unroll
            for (int nn=0;nn<4;nn++) acc[m][nn] = (f32x4){0.f,0.f,0.f,0.f};

        const float* xb = xo + (size_t)n*CL*HWS + pix0;
        float va[8], vb[8];
        {
            const float* xc = xb + (size_t)(8*w8)*HWS;
            #pragma unroll
            for (int j=0;j<8;j++){
                va[j] = xc[(size_t)j*HWS + lane];
                vb[j] = xc[(size_t)j*HWS + 64 + lane];
            }
        }
        int oo = t >> 3, c8 = t & 7;               // A task: o0=oo (wk1), o1=64+oo (wk2)
        for (int kt=0; kt<8; ++kt){
            int c0 = kt*64;
            // A loads first (L2), latency hides under B pack
            const float* ws0 = wk1 + (size_t)oo*CL + c0 + c8*8;
            const float* ws1 = wk2 + (size_t)oo*CL + c0 + c8*8;
            float4 a00 = *(const float4*)ws0, a01 = *(const float4*)(ws0+4);
            float4 a10 = *(const float4*)ws1, a11 = *(const float4*)(ws1+4);
            // B pack from prefetched regs
            uint32_t pa[4], pb[4];
            #pragma unroll
            for (int j=0;j<4;j++){
                pa[j] = pack2(va[2*j], va[2*j+1]);
                pb[j] = pack2(vb[2*j], vb[2*j+1]);
            }
            int offA = (lane*128 + w8*16) ^ ((lane&7)<<4);
            int offB = ((lane+64)*128 + w8*16) ^ ((lane&7)<<4);
            *(uint4*)((char*)Bt + offA) = make_uint4(pa[0],pa[1],pa[2],pa[3]);
            *(uint4*)((char*)Bt + offB) = make_uint4(pb[0],pb[1],pb[2],pb[3]);
            // A pack + write
            {
                int off0 = (oo*128 + c8*16) ^ ((oo&7)<<4);
                int off1 = ((64+oo)*128 + c8*16) ^ ((oo&7)<<4);
                *(uint4*)((char*)At + off0) = make_uint4(pack2(a00.x,a00.y),pack2(a00.z,a00.w),
                                                         pack2(a01.x,a01.y),pack2(a01.z,a01.w));
                *(uint4*)((char*)At + off1) = make_uint4(pack2(a10.x,a10.y),pack2(a10.z,a10.w),
                                                         pack2(a11.x,a11.y),pack2(a11.z,a11.w));
            }
            __syncthreads();
            if (kt < 7){
                const float* xc = xb + (size_t)((kt+1)*64 + 8*w8)*HWS;
                #pragma unroll
                for (int j=0;j<8;j++){
                    va[j] = xc[(size_t)j*HWS + lane];
                    vb[j] = xc[(size_t)j*HWS + 64 + lane];
                }
            }
            #pragma unroll
            for (int ks=0; ks<2; ++ks){
                bf16x8 a[2], bfr[4];
                #pragma unroll
                for (int m=0;m<2;m++){
                    int row = wm*32 + m*16 + r16;
                    int off = (row*128 + ks*64 + (lane>>4)*16) ^ ((row&7)<<4);
                    a[m] = *(const bf16x8*)((const char*)At + off);
                }
                #pragma unroll
                for (int nn=0;nn<4;nn++){
                    int row = wn*64 + nn*16 + r16;
                    int off = (row*128 + ks*64 + (lane>>4)*16) ^ ((row&7)<<4);
                    bfr[nn] = *(const bf16x8*)((const char*)Bt + off);
                }
                #pragma unroll
                for (int m=0;m<2;m++)
                    #pragma unroll
                    for (int nn=0;nn<4;nn++)
                        acc[m][nn] = __builtin_amdgcn_mfma_f32_16x16x32_bf16(a[m], bfr[nn], acc[m][nn], 0, 0, 0);
            }
            __syncthreads();
        }
        // epilogue: bn_relu, f32 stores
        #pragma unroll
        for (int m=0;m<2;m++){
            int obase = wm*32 + m*16 + ((lane>>4)<<2);
            #pragma unroll
            for (int r=0;r<4;r++){
                int o = obase + r;
                int oc = o & 63;
                float sc = ((o<64) ? sk1[oc] : sk2[oc]) * inv;
                float bb =  (o<64) ? bk1[oc] : bk2[oc];
                float* dst = ((o<64) ? k1s : k2s) + ((size_t)n*NECK + oc)*HWS + pix0;
                #pragma unroll
                for (int nn=0;nn<4;nn++){
                    int px = wn*64 + nn*16 + r16;
                    dst[px] = fmaxf(fmaf(acc[m][nn][r], sc, bb), 0.f);
                }
            }
        }
        return;
    }

    // ---- big GEMM: BM=192, BN=128, BK=64, 4 K-steps
    ushort_t* At = (ushort_t*)smem;            // [192][64] swizzled, 24KB
    ushort_t* Bt = (ushort_t*)(smem + 24576);  // [128][64] swizzled, 16KB
    int n = blk >> 7;
    int pix0 = (blk & 127) << 7;

    f32x4 acc[3][4];
    #pragma unroll
    for (int m=0;m<3;m++)
        #pragma unroll
        for (int nn=0;nn<4;nn++) acc[m][nn] = (f32x4){0.f,0.f,0.f,0.f};

    const float* xb = x + (size_t)n*CH*HW + pix0;
    float va[8], vb[8];
    {
        const float* xc = xb + (size_t)(8*w8)*HW;
        #pragma unroll
        for (int j=0;j<8;j++){
            va[j] = xc[(size_t)j*HW + lane];
            vb[j] = xc[(size_t)j*HW + 64 + lane];
        }
    }
    int oo = t >> 3, c8 = t & 7;               // A tasks: o = i*64+oo, src i: wv1/wq1/wq2
    for (int kt=0; kt<4; ++kt){
        int c0 = kt*64;
        // A loads first (L2)
        const float* ws0 = wv1 + (size_t)oo*CH + c0 + c8*8;
        const float* ws1 = wq1 + (size_t)oo*CH + c0 + c8*8;
        const float* ws2 = wq2 + (size_t)oo*CH + c0 + c8*8;
        float4 a00 = *(const float4*)ws0, a01 = *(const float4*)(ws0+4);
        float4 a10 = *(const float4*)ws1, a11 = *(const float4*)(ws1+4);
        float4 a20 = *(const float4*)ws2, a21 = *(const float4*)(ws2+4);
        // B pack from prefetched regs
        uint32_t pa[4], pb[4];
        #pragma unroll
        for (int j=0;j<4;j++){
            pa[j] = pack2(va[2*j], va[2*j+1]);
            pb[j] = pack2(vb[2*j], vb[2*j+1]);
        }
        int c2 = w8*16;
        int offA = (lane*128 + c2) ^ ((lane&7)<<4);
        int offB = ((lane+64)*128 + c2) ^ ((lane&7)<<4);
        *(uint4*)((char*)Bt + offA) = make_uint4(pa[0],pa[1],pa[2],pa[3]);
        *(uint4*)((char*)Bt + offB) = make_uint4(pb[0],pb[1],pb[2],pb[3]);
        // A pack + write
        {
            int swz = (oo&7)<<4;
            int off0 = ((oo     )*128 + c8*16) ^ swz;
            int off1 = ((oo + 64)*128 + c8*16) ^ swz;
            int off2 = ((oo +128)*128 + c8*16) ^ swz;
            *(uint4*)((char*)At + off0) = make_uint4(pack2(a00.x,a00.y),pack2(a00.z,a00.w),
                                                     pack2(a01.x,a01.y),pack2(a01.z,a01.w));
            *(uint4*)((char*)At + off1) = make_uint4(pack2(a10.x,a10.y),pack2(a10.z,a10.w),
                                                     pack2(a11.x,a11.y),pack2(a11.z,a11.w));
            *(uint4*)((char*)At + off2) = make_uint4(pack2(a20.x,a20.y),pack2(a20.z,a20.w),
                                                     pack2(a21.x,a21.y),pack2(a21.z,a21.w));
        }
        __syncthreads();
        if (kt < 3){
            const float* xc = xb + (size_t)((kt+1)*64 + 8*w8)*HW;
            #pragma unroll
            for (int j=0;j<8;j++){
                va[j] = xc[(size_t)j*HW + lane];
                vb[j] = xc[(size_t)j*HW + 64 + lane];
            }
        }
        #pragma unroll
        for (int ks=0; ks<2; ++ks){
            bf16x8 a[3], bfr[4];
            #pragma unroll
            for (int m=0;m<3;m++){
                int row = wm*48 + m*16 + r16;
                int off = (row*128 + ks*64 + (lane>>4)*16) ^ ((row&7)<<4);
                a[m] = *(const bf16x8*)((const char*)At + off);
            }
            #pragma unroll
            for (int nn=0;nn<4;nn++){
                int row = wn*64 + nn*16 + r16;
                int off = (row*128 + ks*64 + (lane>>4)*16) ^ ((row&7)<<4);
                bfr[nn] = *(const bf16x8*)((const char*)Bt + off);
            }
            #pragma unroll
            for (int m=0;m<3;m++)
                #pragma unroll
                for (int nn=0;nn<4;nn++)
                    acc[m][nn] = __builtin_amdgcn_mfma_f32_16x16x32_bf16(a[m], bfr[nn], acc[m][nn], 0, 0, 0);
        }
        __syncthreads();
    }
    // epilogue
    #pragma unroll
    for (int m=0;m<3;m++){
        int obase = wm*48 + m*16 + ((lane>>4)<<2);
        #pragma unroll
        for (int r=0;r<4;r++){
            int o = obase + r;
            int grp = o >> 6, oc = o & 63;
            float sc = 1.f, bb = 0.f;
            ushort_t* dst;
            if (grp == 0) dst = value;
            else if (grp == 1){ sc = s1[oc]*inv; bb = b1[oc]; dst = query; }
            else              { sc = s2[oc]*inv; bb = b2[oc]; dst = query2; }
            #pragma unroll
            for (int nn=0;nn<4;nn++){
                int pix = pix0 + wn*64 + nn*16 + r16;
                float v = acc[m][nn][r];
                if (grp) v = fmaxf(fmaf(v, sc, bb), 0.f);
                dst[((size_t)(n*NECK + oc))*HW + pix] = f2bf(v);
            }
        }
    }
}

// ---------------- K3: MFMA gates. blocks 0..255 scale-1 (P=16, L=1024, ch 0..31),
//                  256..511 scale-2 (P=64, L=256, ch 32..63). 256 thr (4 waves).
__global__ __launch_bounds__(256) void k_gates(
    const ushort_t* __restrict__ query, const float* __restrict__ k1small,
    float* __restrict__ gate1, float* __restrict__ gate2)
{
    __shared__ __align__(16) char smem[69632];   // ksm 4K | qt 32K | kt 32K  (pw/simM alias front)
    int bid = blockIdx.x;
    int t = threadIdx.x;
    int lane = t & 63, wv = t >> 6;
    int r16 = lane & 15, g = lane >> 4;
    float* ksm = (float*)smem;
    ushort_t* qt = (ushort_t*)(smem + 4096);
    ushort_t* kt = (ushort_t*)(smem + 4096 + 32768);

    if (bid < 256){
        // ---- scale 1: sim[16][16] over L=1024
        int n = bid >> 5, c = bid & 31;
        const float* ks = k1small + (size_t)(n*NECK + c)*HWS;
        #pragma unroll
        for (int i=0;i<4;i++) ksm[i*256+t] = ks[i*256+t];
        __syncthreads();
        const ushort_t* qb = query + (size_t)(n*NECK + c)*HW;
        #pragma unroll
        for (int i=0;i<8;i++){
            int task = i*256 + t;            // 2048 = 16p x 128 c8
            int p = task >> 7, c8 = task & 127;
            int ly = c8 >> 2, lx8 = (c8 & 3)*8;
            int h = (p>>2)*32 + ly, w = (p&3)*32 + lx8;
            bf16x8 qv = *(const bf16x8*)(qb + h*W_ + w);
            int off = (p*2048 + c8*16) ^ ((p&7)<<4);
            *(bf16x8*)((char*)qt + off) = qv;
            float yf = h*SC31; int y0=(int)yf; int y1=min(y0+1,31); float fy=yf-(float)y0;
            bfpack pk;
            #pragma unroll
            for (int j=0;j<8;j++){
                int ww = w + j;
                float xf = ww*SC31; int x0=(int)xf; int x1=min(x0+1,31); float fx=xf-(float)x0;
                float a=ksm[y0*32+x0], b=ksm[y0*32+x1], cc=ksm[y1*32+x0], d=ksm[y1*32+x1];
                float r0=a+(b-a)*fx, r1=cc+(d-cc)*fx;
                pk.u[j] = f2bf(r0 + (r1-r0)*fy);
            }
            *(bf16x8*)((char*)kt + off) = pk.v;
        }
        __syncthreads();
        // wave wv accumulates K-chunk [wv*256, +256)
        f32x4 acc = (f32x4){0.f,0.f,0.f,0.f};
        #pragma unroll
        for (int k8=0; k8<8; ++k8){
            int l0 = wv*256 + k8*32 + g*8;
            int off = (r16*2048 + l0*2) ^ ((r16&7)<<4);
            bf16x8 av = *(const bf16x8*)((char*)qt + off);
            bf16x8 bv = *(const bf16x8*)((char*)kt + off);
            acc = __builtin_amdgcn_mfma_f32_16x16x32_bf16(av, bv, acc, 0, 0, 0);
        }
        __syncthreads();                      // qt/kt reads done; aliasing below is safe
        float* pw = (float*)smem;             // [4][256]
        #pragma unroll
        for (int r=0;r<4;r++)
            pw[wv*256 + (g*4+r)*16 + r16] = acc[r];
        __syncthreads();
        float* simM = (float*)(smem + 4096);  // [256]
        float s = pw[t] + pw[256+t] + pw[512+t] + pw[768+t];
        simM[t] = sigmoidf_(s);
        __syncthreads();
        if (t < 16){
            float rs=0.f, cs=0.f;
            #pragma unroll
            for (int q=0;q<16;q++) rs += simM[t*16+q];
            #pragma unroll
            for (int p=0;p<16;p++) cs += simM[p*16+t];
            gate1[(size_t)(n*32 + c)*16 + t] = (rs + cs) * (1.0f/16.0f);
        }
    } else {
        // ---- scale 2: sim[64][64] over L=256
        int b2 = bid - 256;
        int n = b2 >> 5, cl = b2 & 31, c = 32 + cl;
        const float* ks = k1small + (size_t)(n*NECK + c)*HWS;
        #pragma unroll
        for (int i=0;i<4;i++) ksm[i*256+t] = ks[i*256+t];
        __syncthreads();
        const ushort_t* qb = query + (size_t)(n*NECK + c)*HW;
        #pragma unroll
        for (int i=0;i<8;i++){
            int task = i*256 + t;            // 2048 = 64p x 32 c8
            int p = task >> 5, c8 = task & 31;
            int ly = c8 >> 1, lx8 = (c8 & 1)*8;
            int h = (p>>3)*16 + ly, w = (p&7)*16 + lx8;
            bf16x8 qv = *(const bf16x8*)(qb + h*W_ + w);
            int off = (p*512 + c8*16) ^ ((p&7)<<4);
            *(bf16x8*)((char*)qt + off) = qv;
            float yf = h*SC31; int y0=(int)yf; int y1=min(y0+1,31); float fy=yf-(float)y0;
            bfpack pk;
            #pragma unroll
            for (int j=0;j<8;j++){
                int ww = w + j;
                float xf = ww*SC31; int x0=(int)xf; int x1=min(x0+1,31); float fx=xf-(float)x0;
                float a=ksm[y0*32+x0], b=ksm[y0*32+x1], cc=ksm[y1*32+x0], d=ksm[y1*32+x1];
                float r0=a+(b-a)*fx, r1=cc+(d-cc)*fx;
                pk.u[j] = f2bf(r0 + (r1-r0)*fy);
            }
            *(bf16x8*)((char*)kt + off) = pk.v;
        }
        __syncthreads();
        // wave wv owns p-rows [wv*16, +16), all 64 q, full K=256
        f32x4 acc2[4];
        #pragma unroll
        for (int qc=0;qc<4;qc++) acc2[qc] = (f32x4){0.f,0.f,0.f,0.f};
        #pragma unroll
        for (int k8=0; k8<8; ++k8){
            int l0 = k8*32 + g*8;
            int offA = ((wv*16 + r16)*512 + l0*2) ^ ((r16&7)<<4);
            bf16x8 av = *(const bf16x8*)((char*)qt + offA);
            #pragma unroll
            for (int qc=0;qc<4;qc++){
                int offB = ((qc*16 + r16)*512 + l0*2) ^ ((r16&7)<<4);
                bf16x8 bv = *(const bf16x8*)((char*)kt + offB);
                acc2[qc] = __builtin_amdgcn_mfma_f32_16x16x32_bf16(av, bv, acc2[qc], 0, 0, 0);
            }
        }
        __syncthreads();                      // qt/kt reads done; simM aliases front
        float* simM = (float*)smem;           // [64][65]
        #pragma unroll
        for (int qc=0;qc<4;qc++)
            #pragma unroll
            for (int r=0;r<4;r++){
                int p = wv*16 + g*4 + r, q = qc*16 + r16;
                simM[p*65 + q] = sigmoidf_(acc2[qc][r]);
            }
        __syncthreads();
        if (t < 64){
            float rs=0.f, cs=0.f;
            for (int q=0;q<64;q++) rs += simM[t*65 + q];
            for (int p=0;p<64;p++) cs += simM[p*65 + t];
            gate2[(size_t)(n*32 + cl)*64 + t] = (rs + cs) * (1.0f/64.0f);
        }
    }
}

// ---------------- K4: context build + final conv via bf16 MFMA (A direct from global)
// block = 1 image-row (128 px), 512 threads (8 waves: 4M x 2N), BM=256, BN=128, K=128
__global__ __launch_bounds__(512, 4) void k_final_mfma(
    const ushort_t* __restrict__ value, const ushort_t* __restrict__ query2,
    const float* __restrict__ k2small,
    const float* __restrict__ gate1, const float* __restrict__ gate2,
    const ushort_t* __restrict__ Wzb,   // [256][128] bf16
    const float* __restrict__ alpha_p, const float* __restrict__ gamma_p,
    float* __restrict__ out)
{
    __shared__ __align__(16) char smem[59392];  // Ct 32K | g1s 2K | g2s 8K | k2r 16K
    ushort_t* Ct = (ushort_t*)smem;
    float* g1s = (float*)(smem + 32768);
    float* g2s = (float*)(smem + 34816);
    float* k2r = (float*)(smem + 43008);        // [2][2048]
    int blk = blockIdx.x;
    int n = blk >> 7, h = blk & 127;
    int pix0 = h << 7;
    int t = threadIdx.x;
    int lane = t & 63;
    int wid = t >> 6;
    int wm = wid >> 1, wn = wid & 1;

    int px = t & 127, qd = t >> 7;              // 16-channel quad
    // EARLY: issue all value/query2 loads; they fly under the LDS staging below
    const size_t vbase = (size_t)n*NECK*HW + pix0 + px;
    ushort_t vreg[16], qreg[16];
    #pragma unroll
    for (int i=0;i<16;i++){
        int c = qd*16 + i;
        vreg[i] = value [vbase + (size_t)c*HW];
        qreg[i] = query2[vbase + (size_t)c*HW];
    }

    float alpha = alpha_p[0], gamma = gamma_p[0];
    g1s[t & 511] = gate1[(size_t)n*512 + (t & 511)];
    #pragma unroll
    for (int i=0;i<4;i++) g2s[i*512 + t] = gate2[(size_t)n*2048 + i*512 + t];

    float yf = h * SC31;
    int y0 = (int)yf, y1 = min(y0+1, 31);
    float fy = yf - (float)y0;
    #pragma unroll
    for (int i=0;i<8;i++){
        int e = i*512 + t;              // 4096
        int buf = e >> 11, c = (e >> 5) & 63, xx = e & 31;
        k2r[buf*2048 + c*32 + xx] = k2small[((size_t)n*NECK + c)*HWS + (buf ? y1 : y0)*32 + xx];
    }
    __syncthreads();

    // ctx build
    float xf = px * SC31;
    int x0 = (int)xf, x1 = min(x0+1, 31);
    float fx = xf - (float)x0;
    int patch1 = (h>>5)*4 + (px>>5);
    int patch2 = (h>>4)*8 + (px>>4);
    // gate half: ch = qd*16 + j*8 + i
    #pragma unroll
    for (int j=0;j<2;j++){
        bfpack pk;
        #pragma unroll
        for (int i=0;i<8;i++){
            int ch = qd*16 + j*8 + i;
            float g = (ch < 32) ? g1s[ch*16 + patch1] : g2s[(ch-32)*64 + patch2];
            pk.u[i] = f2bf(alpha * g * bf2f(vreg[j*8+i]));
        }
        int off = (px*256 + qd*32 + j*16) ^ ((px&7)<<4);
        *(bf16x8*)((char*)Ct + off) = pk.v;
    }
    // dense half: ctx[64+c] = gamma * v * sigmoid(q2 * bilin(k2))
    #pragma unroll
    for (int j=0;j<2;j++){
        bfpack pk;
        #pragma unroll
        for (int i=0;i<8;i++){
            int c = qd*16 + j*8 + i;
            float vv = bf2f(vreg[j*8+i]);
            float q2 = bf2f(qreg[j*8+i]);
            float r0 = k2r[c*32+x0];      r0 += (k2r[c*32+x1] - r0)*fx;
            float r1 = k2r[2048+c*32+x0]; r1 += (k2r[2048+c*32+x1] - r1)*fx;
            float kv = r0 + (r1 - r0)*fy;
            pk.u[i] = f2bf(gamma * vv * sigmoidf_(q2*kv));
        }
        int off = (px*256 + 128 + qd*32 + j*16) ^ ((px&7)<<4);
        *(bf16x8*)((char*)Ct + off) = pk.v;
    }
    __syncthreads();

    // MFMA: wave tile 64(o) x 64(px), K=128 in 4 steps; A-frags direct from global (L2)
    f32x4 acc[4][4];
    #pragma unroll
    for (int m=0;m<4;m++)
        #pragma unroll
        for (int nn=0;nn<4;nn++) acc[m][nn] = (f32x4){0.f,0.f,0.f,0.f};
    #pragma unroll
    for (int ks=0; ks<4; ++ks){
        bf16x8 a[4], b[4];
        #pragma unroll
        for (int m=0;m<4;m++){
            int row = wm*64 + m*16 + (lane&15);
            a[m] = *(const bf16x8*)(Wzb + row*128 + ks*32 + (lane>>4)*8);
        }
        #pragma unroll
        for (int nn=0;nn<4;nn++){
            int row = wn*64 + nn*16 + (lane&15);
            int off = (row*256 + ks*64 + (lane>>4)*16) ^ ((row&7)<<4);
            b[nn] = *(const bf16x8*)((const char*)Ct + off);
        }
        #pragma unroll
        for (int m=0;m<4;m++)
            #pragma unroll
            for (int nn=0;nn<4;nn++)
                acc[m][nn] = __builtin_amdgcn_mfma_f32_16x16x32_bf16(a[m], b[nn], acc[m][nn], 0, 0, 0);
    }

    // epilogue: o = row, px = col
    #pragma unroll
    for (int m=0;m<4;m++){
        int obase = wm*64 + m*16 + ((lane>>4)<<2);
        #pragma unroll
        for (int r=0;r<4;r++){
            int o = obase + r;
            float* dst = out + ((size_t)(n*CH + o))*HW + pix0 + wn*64 + (lane&15);
            #pragma unroll
            for (int nn=0;nn<4;nn++)
                dst[nn*16] = acc[m][nn][r];
        }
    }
}

extern "C" void kernel_launch(void* const* d_in, const int* in_sizes, int n_in,
                              void* d_out, int out_size, void* d_ws, size_t ws_size,
                              hipStream_t stream) {
    const float* x0  = (const float*)d_in[0];
    const float* xo  = (const float*)d_in[1];
    const float* wq1 = (const float*)d_in[2];
    const float* s1  = (const float*)d_in[3];
    const float* b1  = (const float*)d_in[4];
    const float* wk1 = (const float*)d_in[5];
    const float* sk1 = (const float*)d_in[6];
    const float* bk1 = (const float*)d_in[7];
    const float* wv1 = (const float*)d_in[8];
    const float* wq2 = (const float*)d_in[9];
    const float* s2  = (const float*)d_in[10];
    const float* b2  = (const float*)d_in[11];
    const float* wk2 = (const float*)d_in[12];
    const float* sk2 = (const float*)d_in[13];
    const float* bk2 = (const float*)d_in[14];
    const float* wz  = (const float*)d_in[15];
    const float* alp = (const float*)d_in[16];
    const float* gam = (const float*)d_in[17];

    // workspace layout (all 16B-aligned): ~54 MB total
    ushort_t* value  = (ushort_t*)d_ws;          // 8*64*16384
    ushort_t* query  = value  + 8388608;
    ushort_t* query2 = query  + 8388608;
    float*    k1s    = (float*)(query2 + 8388608);   // 8*64*1024
    float*    k2s    = k1s + 524288;
    float*    g1     = k2s + 524288;             // 8*32*16
    float*    g2     = g1 + 4096;                // 8*32*64
    ushort_t* Wzb    = (ushort_t*)(g2 + 16384);  // 256*128

    k_phase1<<<dim3(1104), dim3(512), 0, stream>>>(
        x0, xo, wv1, wq1, wq2, wk1, wk2, s1, b1, s2, b2, sk1, bk1, sk2, bk2, wz,
        value, query, query2, k1s, k2s, Wzb);
    k_gates<<<dim3(512), dim3(256), 0, stream>>>(query, k1s, g1, g2);
    k_final_mfma<<<dim3(1024), dim3(512), 0, stream>>>(value, query2, k2s, g1, g2, Wzb,
                                                       alp, gam, (float*)d_out);
}

// Round 8
// 125.972 us; speedup vs baseline: 5.0875x; 1.0142x over previous
//
#include <hip/hip_runtime.h>
#include <hip/hip_bf16.h>
#include <math.h>
#include <stdint.h>

#define N_    8
#define CH    256
#define CL    512
#define NECK  64
#define H_    128
#define W_    128
#define HW    16384
#define HWS   1024
#define EPSB  1e-5f
#define SC31  (31.0f/127.0f)

typedef unsigned short ushort_t;
typedef __attribute__((ext_vector_type(8))) short bf16x8;
typedef __attribute__((ext_vector_type(4))) float f32x4;

union bfpack { ushort_t u[8]; bf16x8 v; };

__device__ __forceinline__ float sigmoidf_(float x){ return 1.0f/(1.0f + __expf(-x)); }

__device__ __forceinline__ ushort_t f2bf(float x){
    union { __hip_bfloat16 h; ushort_t u; } cv;
    cv.h = __float2bfloat16(x);              // RNE, compiler fuses pairs to v_cvt_pk_bf16_f32
    return cv.u;
}
__device__ __forceinline__ uint32_t pack2(float lo, float hi){
    return (uint32_t)f2bf(lo) | ((uint32_t)f2bf(hi) << 16);
}
__device__ __forceinline__ float bf2f(ushort_t b){
    union { uint32_t u; float f; } v; v.u = ((uint32_t)b) << 16;
    return v.f;
}

// ---------------- K1: phase-1 single-round launch, 576 blocks x 512 threads
// blocks 0..511 : big GEMM, TWO tiles each (tile = blk, blk+512):
//                 C[192][px] = W[192][256] * X[256][px], BM=192, BN=128, BK=64
// blocks 512..575: wz pack (512 elems) + small conv MFMA tile (1 of 64):
//                 C[128][px] = Wk[128][512] * Xo[512][px]
__global__ __launch_bounds__(512) void k_phase1(
    const float* __restrict__ x,       // [8][256][16384]
    const float* __restrict__ xo,      // [8][512][1024]
    const float* __restrict__ wv1, const float* __restrict__ wq1, const float* __restrict__ wq2,
    const float* __restrict__ wk1, const float* __restrict__ wk2,
    const float* __restrict__ s1, const float* __restrict__ b1,
    const float* __restrict__ s2, const float* __restrict__ b2,
    const float* __restrict__ sk1, const float* __restrict__ bk1,
    const float* __restrict__ sk2, const float* __restrict__ bk2,
    const float* __restrict__ wz,
    ushort_t* __restrict__ value, ushort_t* __restrict__ query, ushort_t* __restrict__ query2,
    float* __restrict__ k1s, float* __restrict__ k2s, ushort_t* __restrict__ Wzb)
{
    __shared__ __align__(16) char smem[40960];
    int blk = blockIdx.x;
    int t = threadIdx.x;
    int lane = t & 63, w8 = t >> 6;
    int wm = w8 >> 1, wn = w8 & 1;
    int r16 = lane & 15;
    float inv = rsqrtf(1.0f + EPSB);

    if (blk >= 512){
        int b = blk - 512;                          // 0..63
        // ---- wz pack: 64 blocks x 512 thr x 1 elem
        Wzb[b*512 + t] = f2bf(wz[b*512 + t]);

        // ---- small conv MFMA: BM=128(o), BN=128(px), BK=64, 8 K-steps
        ushort_t* At = (ushort_t*)smem;            // [128][64] swizzled, 16KB
        ushort_t* Bt = (ushort_t*)(smem + 16384);  // [128][64] swizzled, 16KB
        int n = b >> 3, pix0 = (b & 7) << 7;
        f32x4 acc[2][4];
        #pragma unroll
        for (int m=0;m<2;m++)
            #pragma unroll
            for (int nn=0;nn<4;nn++) acc[m][nn] = (f32x4){0.f,0.f,0.f,0.f};

        const float* xb = xo + (size_t)n*CL*HWS + pix0;
        float va[8], vb[8];
        {
            const float* xc = xb + (size_t)(8*w8)*HWS;
            #pragma unroll
            for (int j=0;j<8;j++){
                va[j] = xc[(size_t)j*HWS + lane];
                vb[j] = xc[(size_t)j*HWS + 64 + lane];
            }
        }
        int oo = t >> 3, c8 = t & 7;               // A task: o0=oo (wk1), o1=64+oo (wk2)
        for (int kt=0; kt<8; ++kt){
            int c0 = kt*64;
            const float* ws0 = wk1 + (size_t)oo*CL + c0 + c8*8;
            const float* ws1 = wk2 + (size_t)oo*CL + c0 + c8*8;
            float4 a00 = *(const float4*)ws0, a01 = *(const float4*)(ws0+4);
            float4 a10 = *(const float4*)ws1, a11 = *(const float4*)(ws1+4);
            uint32_t pa[4], pb[4];
            #pragma unroll
            for (int j=0;j<4;j++){
                pa[j] = pack2(va[2*j], va[2*j+1]);
                pb[j] = pack2(vb[2*j], vb[2*j+1]);
            }
            int offA = (lane*128 + w8*16) ^ ((lane&7)<<4);
            int offB = ((lane+64)*128 + w8*16) ^ ((lane&7)<<4);
            *(uint4*)((char*)Bt + offA) = make_uint4(pa[0],pa[1],pa[2],pa[3]);
            *(uint4*)((char*)Bt + offB) = make_uint4(pb[0],pb[1],pb[2],pb[3]);
            {
                int off0 = (oo*128 + c8*16) ^ ((oo&7)<<4);
                int off1 = ((64+oo)*128 + c8*16) ^ ((oo&7)<<4);
                *(uint4*)((char*)At + off0) = make_uint4(pack2(a00.x,a00.y),pack2(a00.z,a00.w),
                                                         pack2(a01.x,a01.y),pack2(a01.z,a01.w));
                *(uint4*)((char*)At + off1) = make_uint4(pack2(a10.x,a10.y),pack2(a10.z,a10.w),
                                                         pack2(a11.x,a11.y),pack2(a11.z,a11.w));
            }
            __syncthreads();
            if (kt < 7){
                const float* xc = xb + (size_t)((kt+1)*64 + 8*w8)*HWS;
                #pragma unroll
                for (int j=0;j<8;j++){
                    va[j] = xc[(size_t)j*HWS + lane];
                    vb[j] = xc[(size_t)j*HWS + 64 + lane];
                }
            }
            #pragma unroll
            for (int ks=0; ks<2; ++ks){
                bf16x8 a[2], bfr[4];
                #pragma unroll
                for (int m=0;m<2;m++){
                    int row = wm*32 + m*16 + r16;
                    int off = (row*128 + ks*64 + (lane>>4)*16) ^ ((row&7)<<4);
                    a[m] = *(const bf16x8*)((const char*)At + off);
                }
                #pragma unroll
                for (int nn=0;nn<4;nn++){
                    int row = wn*64 + nn*16 + r16;
                    int off = (row*128 + ks*64 + (lane>>4)*16) ^ ((row&7)<<4);
                    bfr[nn] = *(const bf16x8*)((const char*)Bt + off);
                }
                #pragma unroll
                for (int m=0;m<2;m++)
                    #pragma unroll
                    for (int nn=0;nn<4;nn++)
                        acc[m][nn] = __builtin_amdgcn_mfma_f32_16x16x32_bf16(a[m], bfr[nn], acc[m][nn], 0, 0, 0);
            }
            __syncthreads();
        }
        #pragma unroll
        for (int m=0;m<2;m++){
            int obase = wm*32 + m*16 + ((lane>>4)<<2);
            #pragma unroll
            for (int r=0;r<4;r++){
                int o = obase + r;
                int oc = o & 63;
                float sc = ((o<64) ? sk1[oc] : sk2[oc]) * inv;
                float bb =  (o<64) ? bk1[oc] : bk2[oc];
                float* dst = ((o<64) ? k1s : k2s) + ((size_t)n*NECK + oc)*HWS + pix0;
                #pragma unroll
                for (int nn=0;nn<4;nn++){
                    int px = wn*64 + nn*16 + r16;
                    dst[px] = fmaxf(fmaf(acc[m][nn][r], sc, bb), 0.f);
                }
            }
        }
        return;
    }

    // ---- big GEMM: two tiles per block (blk, blk+512); BM=192, BN=128, BK=64
    ushort_t* At = (ushort_t*)smem;            // [192][64] swizzled, 24KB
    ushort_t* Bt = (ushort_t*)(smem + 24576);  // [128][64] swizzled, 16KB
    int oo = t >> 3, c8 = t & 7;               // A tasks: o = i*64+oo, src i: wv1/wq1/wq2

    for (int rr=0; rr<2; ++rr){
        int tile = blk + rr*512;
        int n = tile >> 7;
        int pix0 = (tile & 127) << 7;

        f32x4 acc[3][4];
        #pragma unroll
        for (int m=0;m<3;m++)
            #pragma unroll
            for (int nn=0;nn<4;nn++) acc[m][nn] = (f32x4){0.f,0.f,0.f,0.f};

        const float* xb = x + (size_t)n*CH*HW + pix0;
        float va[8], vb[8];
        {
            const float* xc = xb + (size_t)(8*w8)*HW;
            #pragma unroll
            for (int j=0;j<8;j++){
                va[j] = xc[(size_t)j*HW + lane];
                vb[j] = xc[(size_t)j*HW + 64 + lane];
            }
        }
        for (int kt=0; kt<4; ++kt){
            int c0 = kt*64;
            const float* ws0 = wv1 + (size_t)oo*CH + c0 + c8*8;
            const float* ws1 = wq1 + (size_t)oo*CH + c0 + c8*8;
            const float* ws2 = wq2 + (size_t)oo*CH + c0 + c8*8;
            float4 a00 = *(const float4*)ws0, a01 = *(const float4*)(ws0+4);
            float4 a10 = *(const float4*)ws1, a11 = *(const float4*)(ws1+4);
            float4 a20 = *(const float4*)ws2, a21 = *(const float4*)(ws2+4);
            uint32_t pa[4], pb[4];
            #pragma unroll
            for (int j=0;j<4;j++){
                pa[j] = pack2(va[2*j], va[2*j+1]);
                pb[j] = pack2(vb[2*j], vb[2*j+1]);
            }
            int c2 = w8*16;
            int offA = (lane*128 + c2) ^ ((lane&7)<<4);
            int offB = ((lane+64)*128 + c2) ^ ((lane&7)<<4);
            *(uint4*)((char*)Bt + offA) = make_uint4(pa[0],pa[1],pa[2],pa[3]);
            *(uint4*)((char*)Bt + offB) = make_uint4(pb[0],pb[1],pb[2],pb[3]);
            {
                int swz = (oo&7)<<4;
                int off0 = ((oo     )*128 + c8*16) ^ swz;
                int off1 = ((oo + 64)*128 + c8*16) ^ swz;
                int off2 = ((oo +128)*128 + c8*16) ^ swz;
                *(uint4*)((char*)At + off0) = make_uint4(pack2(a00.x,a00.y),pack2(a00.z,a00.w),
                                                         pack2(a01.x,a01.y),pack2(a01.z,a01.w));
                *(uint4*)((char*)At + off1) = make_uint4(pack2(a10.x,a10.y),pack2(a10.z,a10.w),
                                                         pack2(a11.x,a11.y),pack2(a11.z,a11.w));
                *(uint4*)((char*)At + off2) = make_uint4(pack2(a20.x,a20.y),pack2(a20.z,a20.w),
                                                         pack2(a21.x,a21.y),pack2(a21.z,a21.w));
            }
            __syncthreads();
            if (kt < 3){
                const float* xc = xb + (size_t)((kt+1)*64 + 8*w8)*HW;
                #pragma unroll
                for (int j=0;j<8;j++){
                    va[j] = xc[(size_t)j*HW + lane];
                    vb[j] = xc[(size_t)j*HW + 64 + lane];
                }
            }
            #pragma unroll
            for (int ks=0; ks<2; ++ks){
                bf16x8 a[3], bfr[4];
                #pragma unroll
                for (int m=0;m<3;m++){
                    int row = wm*48 + m*16 + r16;
                    int off = (row*128 + ks*64 + (lane>>4)*16) ^ ((row&7)<<4);
                    a[m] = *(const bf16x8*)((const char*)At + off);
                }
                #pragma unroll
                for (int nn=0;nn<4;nn++){
                    int row = wn*64 + nn*16 + r16;
                    int off = (row*128 + ks*64 + (lane>>4)*16) ^ ((row&7)<<4);
                    bfr[nn] = *(const bf16x8*)((const char*)Bt + off);
                }
                #pragma unroll
                for (int m=0;m<3;m++)
                    #pragma unroll
                    for (int nn=0;nn<4;nn++)
                        acc[m][nn] = __builtin_amdgcn_mfma_f32_16x16x32_bf16(a[m], bfr[nn], acc[m][nn], 0, 0, 0);
            }
            __syncthreads();
        }
        // epilogue (registers only; LDS safe to overwrite next tile after last barrier)
        #pragma unroll
        for (int m=0;m<3;m++){
            int obase = wm*48 + m*16 + ((lane>>4)<<2);
            #pragma unroll
            for (int r=0;r<4;r++){
                int o = obase + r;
                int grp = o >> 6, oc = o & 63;
                float sc = 1.f, bb = 0.f;
                ushort_t* dst;
                if (grp == 0) dst = value;
                else if (grp == 1){ sc = s1[oc]*inv; bb = b1[oc]; dst = query; }
                else              { sc = s2[oc]*inv; bb = b2[oc]; dst = query2; }
                #pragma unroll
                for (int nn=0;nn<4;nn++){
                    int pix = pix0 + wn*64 + nn*16 + r16;
                    float v = acc[m][nn][r];
                    if (grp) v = fmaxf(fmaf(v, sc, bb), 0.f);
                    dst[((size_t)(n*NECK + oc))*HW + pix] = f2bf(v);
                }
            }
        }
    }
}

// ---------------- K3: MFMA gates. blocks 0..255 scale-1 (P=16, L=1024, ch 0..31),
//                  256..511 scale-2 (P=64, L=256, ch 32..63). 256 thr (4 waves).
__global__ __launch_bounds__(256) void k_gates(
    const ushort_t* __restrict__ query, const float* __restrict__ k1small,
    float* __restrict__ gate1, float* __restrict__ gate2)
{
    __shared__ __align__(16) char smem[69632];   // ksm 4K | qt 32K | kt 32K  (pw/simM alias front)
    int bid = blockIdx.x;
    int t = threadIdx.x;
    int lane = t & 63, wv = t >> 6;
    int r16 = lane & 15, g = lane >> 4;
    float* ksm = (float*)smem;
    ushort_t* qt = (ushort_t*)(smem + 4096);
    ushort_t* kt = (ushort_t*)(smem + 4096 + 32768);

    if (bid < 256){
        // ---- scale 1: sim[16][16] over L=1024
        int n = bid >> 5, c = bid & 31;
        const float* ks = k1small + (size_t)(n*NECK + c)*HWS;
        #pragma unroll
        for (int i=0;i<4;i++) ksm[i*256+t] = ks[i*256+t];
        __syncthreads();
        const ushort_t* qb = query + (size_t)(n*NECK + c)*HW;
        #pragma unroll
        for (int i=0;i<8;i++){
            int task = i*256 + t;            // 2048 = 16p x 128 c8
            int p = task >> 7, c8 = task & 127;
            int ly = c8 >> 2, lx8 = (c8 & 3)*8;
            int h = (p>>2)*32 + ly, w = (p&3)*32 + lx8;
            bf16x8 qv = *(const bf16x8*)(qb + h*W_ + w);
            int off = (p*2048 + c8*16) ^ ((p&7)<<4);
            *(bf16x8*)((char*)qt + off) = qv;
            float yf = h*SC31; int y0=(int)yf; int y1=min(y0+1,31); float fy=yf-(float)y0;
            bfpack pk;
            #pragma unroll
            for (int j=0;j<8;j++){
                int ww = w + j;
                float xf = ww*SC31; int x0=(int)xf; int x1=min(x0+1,31); float fx=xf-(float)x0;
                float a=ksm[y0*32+x0], b=ksm[y0*32+x1], cc=ksm[y1*32+x0], d=ksm[y1*32+x1];
                float r0=a+(b-a)*fx, r1=cc+(d-cc)*fx;
                pk.u[j] = f2bf(r0 + (r1-r0)*fy);
            }
            *(bf16x8*)((char*)kt + off) = pk.v;
        }
        __syncthreads();
        // wave wv accumulates K-chunk [wv*256, +256)
        f32x4 acc = (f32x4){0.f,0.f,0.f,0.f};
        #pragma unroll
        for (int k8=0; k8<8; ++k8){
            int l0 = wv*256 + k8*32 + g*8;
            int off = (r16*2048 + l0*2) ^ ((r16&7)<<4);
            bf16x8 av = *(const bf16x8*)((char*)qt + off);
            bf16x8 bv = *(const bf16x8*)((char*)kt + off);
            acc = __builtin_amdgcn_mfma_f32_16x16x32_bf16(av, bv, acc, 0, 0, 0);
        }
        __syncthreads();                      // qt/kt reads done; aliasing below is safe
        float* pw = (float*)smem;             // [4][256]
        #pragma unroll
        for (int r=0;r<4;r++)
            pw[wv*256 + (g*4+r)*16 + r16] = acc[r];
        __syncthreads();
        float* simM = (float*)(smem + 4096);  // [256]
        float s = pw[t] + pw[256+t] + pw[512+t] + pw[768+t];
        simM[t] = sigmoidf_(s);
        __syncthreads();
        if (t < 16){
            float rs=0.f, cs=0.f;
            #pragma unroll
            for (int q=0;q<16;q++) rs += simM[t*16+q];
            #pragma unroll
            for (int p=0;p<16;p++) cs += simM[p*16+t];
            gate1[(size_t)(n*32 + c)*16 + t] = (rs + cs) * (1.0f/16.0f);
        }
    } else {
        // ---- scale 2: sim[64][64] over L=256
        int b2 = bid - 256;
        int n = b2 >> 5, cl = b2 & 31, c = 32 + cl;
        const float* ks = k1small + (size_t)(n*NECK + c)*HWS;
        #pragma unroll
        for (int i=0;i<4;i++) ksm[i*256+t] = ks[i*256+t];
        __syncthreads();
        const ushort_t* qb = query + (size_t)(n*NECK + c)*HW;
        #pragma unroll
        for (int i=0;i<8;i++){
            int task = i*256 + t;            // 2048 = 64p x 32 c8
            int p = task >> 5, c8 = task & 31;
            int ly = c8 >> 1, lx8 = (c8 & 1)*8;
            int h = (p>>3)*16 + ly, w = (p&7)*16 + lx8;
            bf16x8 qv = *(const bf16x8*)(qb + h*W_ + w);
            int off = (p*512 + c8*16) ^ ((p&7)<<4);
            *(bf16x8*)((char*)qt + off) = qv;
            float yf = h*SC31; int y0=(int)yf; int y1=min(y0+1,31); float fy=yf-(float)y0;
            bfpack pk;
            #pragma unroll
            for (int j=0;j<8;j++){
                int ww = w + j;
                float xf = ww*SC31; int x0=(int)xf; int x1=min(x0+1,31); float fx=xf-(float)x0;
                float a=ksm[y0*32+x0], b=ksm[y0*32+x1], cc=ksm[y1*32+x0], d=ksm[y1*32+x1];
                float r0=a+(b-a)*fx, r1=cc+(d-cc)*fx;
                pk.u[j] = f2bf(r0 + (r1-r0)*fy);
            }
            *(bf16x8*)((char*)kt + off) = pk.v;
        }
        __syncthreads();
        // wave wv owns p-rows [wv*16, +16), all 64 q, full K=256
        f32x4 acc2[4];
        #pragma unroll
        for (int qc=0;qc<4;qc++) acc2[qc] = (f32x4){0.f,0.f,0.f,0.f};
        #pragma unroll
        for (int k8=0; k8<8; ++k8){
            int l0 = k8*32 + g*8;
            int offA = ((wv*16 + r16)*512 + l0*2) ^ ((r16&7)<<4);
            bf16x8 av = *(const bf16x8*)((char*)qt + offA);
            #pragma unroll
            for (int qc=0;qc<4;qc++){
                int offB = ((qc*16 + r16)*512 + l0*2) ^ ((r16&7)<<4);
                bf16x8 bv = *(const bf16x8*)((char*)kt + offB);
                acc2[qc] = __builtin_amdgcn_mfma_f32_16x16x32_bf16(av, bv, acc2[qc], 0, 0, 0);
            }
        }
        __syncthreads();                      // qt/kt reads done; simM aliases front
        float* simM = (float*)smem;           // [64][65]
        #pragma unroll
        for (int qc=0;qc<4;qc++)
            #pragma unroll
            for (int r=0;r<4;r++){
                int p = wv*16 + g*4 + r, q = qc*16 + r16;
                simM[p*65 + q] = sigmoidf_(acc2[qc][r]);
            }
        __syncthreads();
        if (t < 64){
            float rs=0.f, cs=0.f;
            for (int q=0;q<64;q++) rs += simM[t*65 + q];
            for (int p=0;p<64;p++) cs += simM[p*65 + t];
            gate2[(size_t)(n*32 + cl)*64 + t] = (rs + cs) * (1.0f/64.0f);
        }
    }
}

// ---------------- K4: context build + final conv via bf16 MFMA (A direct from global)
// block = 1 image-row (128 px), 512 threads (8 waves: 4M x 2N), BM=256, BN=128, K=128
__global__ __launch_bounds__(512, 4) void k_final_mfma(
    const ushort_t* __restrict__ value, const ushort_t* __restrict__ query2,
    const float* __restrict__ k2small,
    const float* __restrict__ gate1, const float* __restrict__ gate2,
    const ushort_t* __restrict__ Wzb,   // [256][128] bf16
    const float* __restrict__ alpha_p, const float* __restrict__ gamma_p,
    float* __restrict__ out)
{
    __shared__ __align__(16) char smem[59392];  // Ct 32K | g1s 2K | g2s 8K | k2r 16K
    ushort_t* Ct = (ushort_t*)smem;
    float* g1s = (float*)(smem + 32768);
    float* g2s = (float*)(smem + 34816);
    float* k2r = (float*)(smem + 43008);        // [2][2048]
    int blk = blockIdx.x;
    int n = blk >> 7, h = blk & 127;
    int pix0 = h << 7;
    int t = threadIdx.x;
    int lane = t & 63;
    int wid = t >> 6;
    int wm = wid >> 1, wn = wid & 1;

    int px = t & 127, qd = t >> 7;              // 16-channel quad
    // EARLY: issue all value/query2 loads; they fly under the LDS staging below
    const size_t vbase = (size_t)n*NECK*HW + pix0 + px;
    ushort_t vreg[16], qreg[16];
    #pragma unroll
    for (int i=0;i<16;i++){
        int c = qd*16 + i;
        vreg[i] = value [vbase + (size_t)c*HW];
        qreg[i] = query2[vbase + (size_t)c*HW];
    }

    float alpha = alpha_p[0], gamma = gamma_p[0];
    g1s[t & 511] = gate1[(size_t)n*512 + (t & 511)];
    #pragma unroll
    for (int i=0;i<4;i++) g2s[i*512 + t] = gate2[(size_t)n*2048 + i*512 + t];

    float yf = h * SC31;
    int y0 = (int)yf, y1 = min(y0+1, 31);
    float fy = yf - (float)y0;
    #pragma unroll
    for (int i=0;i<8;i++){
        int e = i*512 + t;              // 4096
        int buf = e >> 11, c = (e >> 5) & 63, xx = e & 31;
        k2r[buf*2048 + c*32 + xx] = k2small[((size_t)n*NECK + c)*HWS + (buf ? y1 : y0)*32 + xx];
    }
    __syncthreads();

    // ctx build
    float xf = px * SC31;
    int x0 = (int)xf, x1 = min(x0+1, 31);
    float fx = xf - (float)x0;
    int patch1 = (h>>5)*4 + (px>>5);
    int patch2 = (h>>4)*8 + (px>>4);
    // gate half: ch = qd*16 + j*8 + i
    #pragma unroll
    for (int j=0;j<2;j++){
        bfpack pk;
        #pragma unroll
        for (int i=0;i<8;i++){
            int ch = qd*16 + j*8 + i;
            float g = (ch < 32) ? g1s[ch*16 + patch1] : g2s[(ch-32)*64 + patch2];
            pk.u[i] = f2bf(alpha * g * bf2f(vreg[j*8+i]));
        }
        int off = (px*256 + qd*32 + j*16) ^ ((px&7)<<4);
        *(bf16x8*)((char*)Ct + off) = pk.v;
    }
    // dense half: ctx[64+c] = gamma * v * sigmoid(q2 * bilin(k2))
    #pragma unroll
    for (int j=0;j<2;j++){
        bfpack pk;
        #pragma unroll
        for (int i=0;i<8;i++){
            int c = qd*16 + j*8 + i;
            float vv = bf2f(vreg[j*8+i]);
            float q2 = bf2f(qreg[j*8+i]);
            float r0 = k2r[c*32+x0];      r0 += (k2r[c*32+x1] - r0)*fx;
            float r1 = k2r[2048+c*32+x0]; r1 += (k2r[2048+c*32+x1] - r1)*fx;
            float kv = r0 + (r1 - r0)*fy;
            pk.u[i] = f2bf(gamma * vv * sigmoidf_(q2*kv));
        }
        int off = (px*256 + 128 + qd*32 + j*16) ^ ((px&7)<<4);
        *(bf16x8*)((char*)Ct + off) = pk.v;
    }
    __syncthreads();

    // MFMA: wave tile 64(o) x 64(px), K=128 in 4 steps; A-frags direct from global (L2)
    f32x4 acc[4][4];
    #pragma unroll
    for (int m=0;m<4;m++)
        #pragma unroll
        for (int nn=0;nn<4;nn++) acc[m][nn] = (f32x4){0.f,0.f,0.f,0.f};
    #pragma unroll
    for (int ks=0; ks<4; ++ks){
        bf16x8 a[4], b[4];
        #pragma unroll
        for (int m=0;m<4;m++){
            int row = wm*64 + m*16 + (lane&15);
            a[m] = *(const bf16x8*)(Wzb + row*128 + ks*32 + (lane>>4)*8);
        }
        #pragma unroll
        for (int nn=0;nn<4;nn++){
            int row = wn*64 + nn*16 + (lane&15);
            int off = (row*256 + ks*64 + (lane>>4)*16) ^ ((row&7)<<4);
            b[nn] = *(const bf16x8*)((const char*)Ct + off);
        }
        #pragma unroll
        for (int m=0;m<4;m++)
            #pragma unroll
            for (int nn=0;nn<4;nn++)
                acc[m][nn] = __builtin_amdgcn_mfma_f32_16x16x32_bf16(a[m], b[nn], acc[m][nn], 0, 0, 0);
    }

    // epilogue: o = row, px = col
    #pragma unroll
    for (int m=0;m<4;m++){
        int obase = wm*64 + m*16 + ((lane>>4)<<2);
        #pragma unroll
        for (int r=0;r<4;r++){
            int o = obase + r;
            float* dst = out + ((size_t)(n*CH + o))*HW + pix0 + wn*64 + (lane&15);
            #pragma unroll
            for (int nn=0;nn<4;nn++)
                dst[nn*16] = acc[m][nn][r];
        }
    }
}

extern "C" void kernel_launch(void* const* d_in, const int* in_sizes, int n_in,
                              void* d_out, int out_size, void* d_ws, size_t ws_size,
                              hipStream_t stream) {
    const float* x0  = (const float*)d_in[0];
    const float* xo  = (const float*)d_in[1];
    const float* wq1 = (const float*)d_in[2];
    const float* s1  = (const float*)d_in[3];
    const float* b1  = (const float*)d_in[4];
    const float* wk1 = (const float*)d_in[5];
    const float* sk1 = (const float*)d_in[6];
    const float* bk1 = (const float*)d_in[7];
    const float* wv1 = (const float*)d_in[8];
    const float* wq2 = (const float*)d_in[9];
    const float* s2  = (const float*)d_in[10];
    const float* b2  = (const float*)d_in[11];
    const float* wk2 = (const float*)d_in[12];
    const float* sk2 = (const float*)d_in[13];
    const float* bk2 = (const float*)d_in[14];
    const float* wz  = (const float*)d_in[15];
    const float* alp = (const float*)d_in[16];
    const float* gam = (const float*)d_in[17];

    // workspace layout (all 16B-aligned): ~54 MB total
    ushort_t* value  = (ushort_t*)d_ws;          // 8*64*16384
    ushort_t* query  = value  + 8388608;
    ushort_t* query2 = query  + 8388608;
    float*    k1s    = (float*)(query2 + 8388608);   // 8*64*1024
    float*    k2s    = k1s + 524288;
    float*    g1     = k2s + 524288;             // 8*32*16
    float*    g2     = g1 + 4096;                // 8*32*64
    ushort_t* Wzb    = (ushort_t*)(g2 + 16384);  // 256*128

    k_phase1<<<dim3(576), dim3(512), 0, stream>>>(
        x0, xo, wv1, wq1, wq2, wk1, wk2, s1, b1, s2, b2, sk1, bk1, sk2, bk2, wz,
        value, query, query2, k1s, k2s, Wzb);
    k_gates<<<dim3(512), dim3(256), 0, stream>>>(query, k1s, g1, g2);
    k_final_mfma<<<dim3(1024), dim3(512), 0, stream>>>(value, query2, k2s, g1, g2, Wzb,
                                                       alp, gam, (float*)d_out);
}